// Round 10
// baseline (515.107 us; speedup 1.0000x reference)
//
#include <hip/hip_runtime.h>
#include <cstddef>
#include <cstdint>

#define N_NODES 20000
#define N_EDGES 320000

typedef __attribute__((ext_vector_type(8))) short bf8_t;   // 8 x bf16 (MFMA frag)
typedef __attribute__((ext_vector_type(4))) float f4_t;    // MFMA acc / float4
typedef __attribute__((ext_vector_type(2))) float f2_t;
typedef unsigned short bfu;
typedef _Float16 half_t;
typedef __attribute__((ext_vector_type(2))) _Float16 h2_t;
typedef __attribute__((ext_vector_type(4))) _Float16 h4_t;
typedef __attribute__((ext_vector_type(8))) _Float16 h8_t;

__device__ __forceinline__ short f2bf(float f) {
  unsigned u = __float_as_uint(f);
  u += 0x7fff + ((u >> 16) & 1);   // round-to-nearest-even
  return (short)(u >> 16);
}
// |t| on packed f16 (clear sign bits)
__device__ __forceinline__ h2_t abs_h2(h2_t t) {
  unsigned u = __builtin_bit_cast(unsigned, t) & 0x7fff7fffu;
  return __builtin_bit_cast(h2_t, u);
}
__device__ __forceinline__ float dot2h(h2_t a, h2_t b, float c) {
#if __has_builtin(__builtin_amdgcn_fdot2)
  return __builtin_amdgcn_fdot2(a, b, c, false);
#else
  return c + (float)a.x * (float)b.x + (float)a.y * (float)b.y;
#endif
}

// ======================= CSR build =======================
__global__ void count_deg_kernel(const int* __restrict__ dst, int* __restrict__ deg, int e_cnt) {
  int e = blockIdx.x * blockDim.x + threadIdx.x;
  if (e < e_cnt) atomicAdd(&deg[dst[e]], 1);
}

__global__ __launch_bounds__(1024) void scan_kernel(
    const int* __restrict__ deg, int* __restrict__ rowptr,
    int* __restrict__ cursor, int n) {
  __shared__ int sdata[1024];
  constexpr int CH = (N_NODES + 1023) / 1024;   // compile-time -> loc[] stays in regs
  int tid = threadIdx.x;
  int base = tid * CH;
  int loc[CH];
  int s = 0;
  #pragma unroll
  for (int j = 0; j < CH; ++j) {
    int idx = base + j;
    int v = (idx < n) ? deg[idx] : 0;
    loc[j] = s;
    s += v;
  }
  sdata[tid] = s;
  __syncthreads();
  for (int off = 1; off < 1024; off <<= 1) {
    int t = (tid >= off) ? sdata[tid - off] : 0;
    __syncthreads();
    sdata[tid] += t;
    __syncthreads();
  }
  int excl = sdata[tid] - s;
  #pragma unroll
  for (int j = 0; j < CH; ++j) {
    int idx = base + j;
    if (idx < n) { int val = excl + loc[j]; rowptr[idx] = val; cursor[idx] = val; }
  }
  if (tid == 0) rowptr[n] = sdata[1023];
}

__global__ void fill_csr_kernel(const int* __restrict__ src, const int* __restrict__ dst,
                                int* __restrict__ cursor, int* __restrict__ csr_src,
                                int* __restrict__ csr_eid, int e_cnt) {
  int e = blockIdx.x * blockDim.x + threadIdx.x;
  if (e < e_cnt) {
    int pos = atomicAdd(&cursor[dst[e]], 1);
    csr_src[pos] = src[e];
    csr_eid[pos] = e;
  }
}

// ======================= degree-sorted node order (load balancing) ===================
// Aggregation blocks own 4 waves; block retires at the max of its 4 waves' degrees.
// Counting-sort nodes by descending degree so sibling waves get near-equal work.
__global__ void deg_hist_kernel(const int* __restrict__ deg, int* __restrict__ hist, int n) {
  int i = blockIdx.x * blockDim.x + threadIdx.x;
  if (i < n) {
    int b = deg[i]; b = b > 511 ? 511 : b;
    atomicAdd(&hist[511 - b], 1);   // reversed bins -> descending degree
  }
}

__global__ __launch_bounds__(512) void hist_scan_kernel(
    const int* __restrict__ hist, int* __restrict__ hcur) {
  __shared__ int s[512];
  int t = threadIdx.x;
  s[t] = hist[t];
  __syncthreads();
  for (int off = 1; off < 512; off <<= 1) {
    int v = (t >= off) ? s[t - off] : 0;
    __syncthreads();
    s[t] += v;
    __syncthreads();
  }
  hcur[t] = s[t] - hist[t];   // exclusive prefix
}

__global__ void order_scatter_kernel(const int* __restrict__ deg, int* __restrict__ hcur,
                                     int* __restrict__ order, int n) {
  int i = blockIdx.x * blockDim.x + threadIdx.x;
  if (i < n) {
    int b = deg[i]; b = b > 511 ? 511 : b;
    int pos = atomicAdd(&hcur[511 - b], 1);
    order[pos] = i;
  }
}

// ======================= weight prep =======================
__global__ void prep_all_kernel(
    const float* __restrict__ n1l, const float* __restrict__ n1r,
    const float* __restrict__ e1l, const float* __restrict__ e1r,
    const float* __restrict__ n2l, const float* __restrict__ n2r,
    const float* __restrict__ e2l, const float* __restrict__ e2r,
    const float* __restrict__ b2, const float* __restrict__ wp,
    short* __restrict__ t_n1l, short* __restrict__ t_n1r,
    short* __restrict__ t_e1l, short* __restrict__ t_e1r,
    short* __restrict__ t_n2l, short* __restrict__ t_n2r,
    short* __restrict__ t_e2l, short* __restrict__ t_e2r,
    float* __restrict__ wct, float* __restrict__ pc)
{
  int i = blockIdx.x * blockDim.x + threadIdx.x;
  int seg = i >> 14;
  int j = i & 16383;
  if (seg < 4) {
    const float* srcs[4] = {n1l, n1r, e1l, e1r};
    short* dsts[4] = {t_n1l, t_n1r, t_e1l, t_e1r};
    int n = j >> 6, k = j & 63;
    dsts[seg][n * 64 + k] = f2bf(srcs[seg][k * 256 + n]);
  } else if (seg < 8) {
    const float* srcs[4] = {n2l, n2r, e2l, e2r};
    short* dsts[4] = {t_n2l, t_n2r, t_e2l, t_e2r};
    int n = j >> 8, k = j & 255;
    dsts[seg - 4][n * 256 + k] = f2bf(srcs[seg - 4][k * 64 + n]);
  } else if (seg == 8) {
    if (j < 512) {
      int jj = j & 1;
      int k  = j >> 1;
      float s = 0.f;
      for (int c = 0; c < 64; ++c) s = fmaf(e2l[k * 64 + c], wp[c * 2 + jj], s);
      wct[jj * 256 + k] = s;
    } else if (j < 514) {
      int jj = j - 512;
      float s = 0.f;
      for (int c = 0; c < 64; ++c) s = fmaf(b2[c], wp[c * 2 + jj], s);
      pc[jj] = s;
    }
  }
}

// ======================= MFMA projection kernel (dual-chain, fp16 outputs) ==========
template<int K, typename SrcT>
__global__ __launch_bounds__(128) void mfma_proj2_kernel(
    const SrcT* __restrict__ A0,
    const short* __restrict__ Wtl0, const short* __restrict__ Wtr0,
    half_t* __restrict__ xl0, half_t* __restrict__ xr0,
    const SrcT* __restrict__ A1,
    const short* __restrict__ Wtl1, const short* __restrict__ Wtr1,
    half_t* __restrict__ xl1, half_t* __restrict__ xr1,
    const float* __restrict__ att0, const float* __restrict__ att1,
    float* __restrict__ ll0, float* __restrict__ lr0,
    float* __restrict__ ll1, float* __restrict__ lr1,
    int M, int nslices)
{
  constexpr int KC = K / 32;
  int tid = threadIdx.x;
  int w = tid >> 6, lane = tid & 63, quad = lane >> 4, l15 = lane & 15;
  int row_base = (int)blockIdx.x * 64 + w * 32;
  int y = (int)blockIdx.y;
  int z = (int)blockIdx.z;
  const SrcT* A = z ? A1 : A0;
  bool is_l = y < nslices;
  const short* Wt = z ? (is_l ? Wtl1 : Wtr1) : (is_l ? Wtl0 : Wtr0);
  half_t* dst = z ? (is_l ? xl1 : xr1) : (is_l ? xl0 : xr0);
  const float* att = z ? att1 : att0;
  float* lin = z ? (is_l ? ll1 : lr1) : (is_l ? ll0 : lr0);
  int head = is_l ? y : y - nslices;
  int cb = head * 64;
  const float* atp = att + head * 64;
  int STR = nslices * 64;

  bf8_t a[2][KC];
  #pragma unroll
  for (int rt = 0; rt < 2; ++rt) {
    int r = row_base + rt * 16 + l15;
    int rc = r < M ? r : M - 1;
    const SrcT* ap = A + (size_t)rc * K + quad * 8;
    #pragma unroll
    for (int kc = 0; kc < KC; ++kc) {
      bf8_t f;
      if constexpr (sizeof(SrcT) == 4) {
        float4 v0 = *(const float4*)(ap + kc * 32);
        float4 v1 = *(const float4*)(ap + kc * 32 + 4);
        f[0] = f2bf(v0.x); f[1] = f2bf(v0.y); f[2] = f2bf(v0.z); f[3] = f2bf(v0.w);
        f[4] = f2bf(v1.x); f[5] = f2bf(v1.y); f[6] = f2bf(v1.z); f[7] = f2bf(v1.w);
      } else {
        h8_t hv = *(const h8_t*)(ap + kc * 32);
        #pragma unroll
        for (int q = 0; q < 8; ++q) f[q] = f2bf((float)hv[q]);
      }
      a[rt][kc] = f;
    }
  }

  float lacc0 = 0.f, lacc1 = 0.f;
  #pragma unroll
  for (int nt = 0; nt < 4; ++nt) {
    f4_t acc0 = {0.f, 0.f, 0.f, 0.f};
    f4_t acc1 = {0.f, 0.f, 0.f, 0.f};
    const short* wb = Wt + (size_t)(cb + nt * 16 + l15) * K + quad * 8;
    #pragma unroll
    for (int kc = 0; kc < KC; ++kc) {
      bf8_t wf = *(const bf8_t*)(wb + kc * 32);
      acc0 = __builtin_amdgcn_mfma_f32_16x16x32_bf16(wf, a[0][kc], acc0, 0, 0, 0);
      acc1 = __builtin_amdgcn_mfma_f32_16x16x32_bf16(wf, a[1][kc], acc1, 0, 0, 0);
    }
    // att-dot for the linear logit part (cols nt*16 + quad*4 + j of this head)
    f4_t av = *(const f4_t*)(atp + nt * 16 + quad * 4);
    lacc0 += acc0[0] * av[0] + acc0[1] * av[1] + acc0[2] * av[2] + acc0[3] * av[3];
    lacc1 += acc1[0] * av[0] + acc1[1] * av[1] + acc1[2] * av[2] + acc1[3] * av[3];
    #pragma unroll
    for (int rt = 0; rt < 2; ++rt) {
      f4_t acc = rt == 0 ? acc0 : acc1;
      int row = row_base + rt * 16 + l15;
      if (row >= M) continue;
      int col = cb + nt * 16 + quad * 4;
      h4_t pk;
      pk[0] = (_Float16)acc[0]; pk[1] = (_Float16)acc[1];
      pk[2] = (_Float16)acc[2]; pk[3] = (_Float16)acc[3];
      *(h4_t*)&dst[(size_t)row * STR + col] = pk;
    }
  }
  // reduce lacc across the 4 quads (each quad covered a disjoint col subset)
  lacc0 += __shfl_xor(lacc0, 16, 64); lacc0 += __shfl_xor(lacc0, 32, 64);
  lacc1 += __shfl_xor(lacc1, 16, 64); lacc1 += __shfl_xor(lacc1, 32, 64);
  if (quad == 0) {
    int r0 = row_base + l15;
    int r1 = row_base + 16 + l15;
    if (r0 < M) lin[(size_t)r0 * nslices + head] = 0.6f * lacc0;
    if (r1 < M) lin[(size_t)r1 * nslices + head] = 0.6f * lacc1;
  }
}

// ======================= fp32 GEMM (proxy head only) =======================
template<int KIN>
__device__ __forceinline__ void gemm_body(
    const float* __restrict__ A, const float* __restrict__ W, int wld, int cb,
    int block_m, int M, float (&acc)[8][4],
    float (*As)[128 + 4], float (*Ws)[64 + 4])
{
  int tid = threadIdx.x;
  int tx = tid & 15;
  int ty = tid >> 4;
  #pragma unroll
  for (int i = 0; i < 8; ++i)
    #pragma unroll
    for (int j = 0; j < 4; ++j) acc[i][j] = 0.f;

  for (int k0 = 0; k0 < KIN; k0 += 16) {
    #pragma unroll
    for (int rep = 0; rep < 2; ++rep) {
      int ar = (tid >> 2) + rep * 64;
      int ak = (tid & 3) * 4;
      int gr = block_m + ar;
      float4 v = make_float4(0.f, 0.f, 0.f, 0.f);
      if (gr < M) v = *(const float4*)&A[(size_t)gr * KIN + k0 + ak];
      As[ak + 0][ar] = v.x; As[ak + 1][ar] = v.y;
      As[ak + 2][ar] = v.z; As[ak + 3][ar] = v.w;
    }
    {
      int wr = tid >> 4;
      int wc = (tid & 15) * 4;
      float4 v = *(const float4*)&W[(size_t)(k0 + wr) * wld + cb + wc];
      Ws[wr][wc + 0] = v.x; Ws[wr][wc + 1] = v.y;
      Ws[wr][wc + 2] = v.z; Ws[wr][wc + 3] = v.w;
    }
    __syncthreads();
    #pragma unroll
    for (int k = 0; k < 16; ++k) {
      float a[8], w[4];
      #pragma unroll
      for (int i = 0; i < 8; ++i) a[i] = As[k][ty * 8 + i];
      #pragma unroll
      for (int j = 0; j < 4; ++j) w[j] = Ws[k][tx * 4 + j];
      #pragma unroll
      for (int i = 0; i < 8; ++i)
        #pragma unroll
        for (int j = 0; j < 4; ++j) acc[i][j] = fmaf(a[i], w[j], acc[i][j]);
    }
    __syncthreads();
  }
}

template<int KIN, int MODE>
__global__ __launch_bounds__(256) void gemm64_kernel(
    const float* __restrict__ A, const float* __restrict__ W, int wld,
    const float* __restrict__ bias, float* __restrict__ out, int old, int M)
{
  __shared__ float As[16][128 + 4];
  __shared__ float Ws[16][64 + 4];
  float acc[8][4];
  int block_m = (int)blockIdx.x * 128;
  int cb = (int)blockIdx.y * 64;
  gemm_body<KIN>(A, W, wld, cb, block_m, M, acc, As, Ws);

  int tid = threadIdx.x;
  int tx = tid & 15, ty = tid >> 4;
  int gc = cb + tx * 4;
  #pragma unroll
  for (int i = 0; i < 8; ++i) {
    int gr = block_m + ty * 8 + i;
    if (gr >= M) continue;
    size_t idx = (size_t)gr * old + gc;
    float t0 = acc[i][0], t1 = acc[i][1], t2 = acc[i][2], t3 = acc[i][3];
    if (MODE == 3) {
      t0 = fmaxf(t0 + bias[gc + 0], 0.f);
      t1 = fmaxf(t1 + bias[gc + 1], 0.f);
      t2 = fmaxf(t2 + bias[gc + 2], 0.f);
      t3 = fmaxf(t3 + bias[gc + 3], 0.f);
    }
    *(float4*)&out[idx] = make_float4(t0, t1, t2, t3);
  }
}

// ======================= GATv2 aggregation, layer 1 (4 heads fused per wave) ==========
// Waves take d = order[...] (degree-sorted) so the 4 sibling waves of a block have
// near-equal trip counts — block retires at max(sibling degrees), was ~30% waste.
__global__ __launch_bounds__(256) void gat_agg_l1(
    const half_t* __restrict__ xl0, const half_t* __restrict__ xr0,
    const float* __restrict__ att0, const float* __restrict__ bias0,
    half_t* __restrict__ out0,
    const half_t* __restrict__ xl1, const half_t* __restrict__ xr1,
    const float* __restrict__ att1, const float* __restrict__ bias1,
    half_t* __restrict__ out1,
    const float* __restrict__ ll0, const float* __restrict__ lr0,
    const float* __restrict__ ll1, const float* __restrict__ lr1,
    const int* __restrict__ rowptr, const int* __restrict__ csr_src,
    const int* __restrict__ order)
{
  constexpr int GRP = N_NODES / 4;
  int tid = threadIdx.x;
  int w = tid >> 6, lane = tid & 63;
  int egrp = lane >> 5;
  int head = (lane >> 3) & 3;
  int coff = (lane & 31) * 8;
  int bid = (int)blockIdx.x;
  int chain = bid >= GRP ? 1 : 0;
  int d = order[(bid - chain * GRP) * 4 + w];

  const half_t* xl = chain ? xl1 : xl0;
  const half_t* xr = chain ? xr1 : xr0;
  const float* att = chain ? att1 : att0;
  const float* bias = chain ? bias1 : bias0;
  const float* linl = chain ? ll1 : ll0;
  const float* linr = chain ? lr1 : lr0;
  half_t* out = chain ? out1 : out0;

  int row0 = rowptr[d];
  int deg = rowptr[d + 1] - row0;

  h2_t xr2[4], attA[4];
  {
    h8_t xv = *(const h8_t*)&xr[(unsigned)(d * 256 + coff)];
    xr2[0] = h2_t{xv[0], xv[1]}; xr2[1] = h2_t{xv[2], xv[3]};
    xr2[2] = h2_t{xv[4], xv[5]}; xr2[3] = h2_t{xv[6], xv[7]};
    const float* atp = att + coff;
    float4 b0 = *(const float4*)(atp);
    float4 b1 = *(const float4*)(atp + 4);
    attA[0] = h2_t{(_Float16)(0.4f * b0.x), (_Float16)(0.4f * b0.y)};
    attA[1] = h2_t{(_Float16)(0.4f * b0.z), (_Float16)(0.4f * b0.w)};
    attA[2] = h2_t{(_Float16)(0.4f * b1.x), (_Float16)(0.4f * b1.y)};
    attA[3] = h2_t{(_Float16)(0.4f * b1.z), (_Float16)(0.4f * b1.w)};
  }
  float linr_d = linr[(unsigned)(d * 4 + head)];

  auto ld_idx = [&](int k) -> int {
    int idx = k * 2 + egrp;
    int cl = idx < deg ? idx : (deg > 0 ? deg - 1 : 0);
    int pos = deg > 0 ? row0 + cl : 0;
    int sv = csr_src[pos];
    return idx < deg ? sv : d;
  };

  float zloc, a8[8];
  {
    // self loop (counted once via egrp==0 mask)
    h8_t xu = *(const h8_t*)&xl[(unsigned)(d * 256 + coff)];
    float part = 0.f;
    #pragma unroll
    for (int j = 0; j < 4; ++j) {
      h2_t t = h2_t{xu[2 * j], xu[2 * j + 1]} + xr2[j];
      part = dot2h(abs_h2(t), attA[j], part);
    }
    part += __shfl_xor(part, 1, 64);
    part += __shfl_xor(part, 2, 64);
    part += __shfl_xor(part, 4, 64);
    part += linl[(unsigned)(d * 4 + head)] + linr_d;
    float wgt = __expf(part);
    float ws = (egrp == 0) ? wgt : 0.f;
    zloc = ws;
    #pragma unroll
    for (int i = 0; i < 8; ++i) a8[i] = (float)xu[i] * ws;
  }

  int C = (deg + 1) >> 1;
  int s_cur = ld_idx(0);
  h8_t xu_cur = *(const h8_t*)&xl[(unsigned)(s_cur * 256 + coff)];
  float lin_cur = linl[(unsigned)(s_cur * 4 + head)];
  int s_nxt = ld_idx(1);
  for (int k = 0; k < C; ++k) {
    h8_t xu_nxt = *(const h8_t*)&xl[(unsigned)(s_nxt * 256 + coff)];
    float lin_nxt = linl[(unsigned)(s_nxt * 4 + head)];
    int s_n2 = ld_idx(k + 2);
    bool valid = (k * 2 + egrp) < deg;
    float part = 0.f;
    #pragma unroll
    for (int j = 0; j < 4; ++j) {
      h2_t t = h2_t{xu_cur[2 * j], xu_cur[2 * j + 1]} + xr2[j];
      part = dot2h(abs_h2(t), attA[j], part);
    }
    part += __shfl_xor(part, 1, 64);
    part += __shfl_xor(part, 2, 64);
    part += __shfl_xor(part, 4, 64);
    part += lin_cur + linr_d;
    float wgt = valid ? __expf(part) : 0.f;
    zloc += wgt;
    #pragma unroll
    for (int i = 0; i < 8; ++i) a8[i] = fmaf((float)xu_cur[i], wgt, a8[i]);
    xu_cur = xu_nxt; lin_cur = lin_nxt; s_nxt = s_n2;
  }

  // combine the two edge-slot halves
  zloc += __shfl_xor(zloc, 32, 64);
  #pragma unroll
  for (int i = 0; i < 8; ++i) a8[i] += __shfl_xor(a8[i], 32, 64);

  if (egrp == 0) {
    float invz = 1.f / zloc;
    const float* bp = bias + coff;
    float4 c0 = *(const float4*)(bp);
    float4 c1 = *(const float4*)(bp + 4);
    float o[8];
    o[0] = a8[0] * invz + c0.x; o[1] = a8[1] * invz + c0.y;
    o[2] = a8[2] * invz + c0.z; o[3] = a8[3] * invz + c0.w;
    o[4] = a8[4] * invz + c1.x; o[5] = a8[5] * invz + c1.y;
    o[6] = a8[6] * invz + c1.z; o[7] = a8[7] * invz + c1.w;
    #pragma unroll
    for (int i = 0; i < 8; ++i) o[i] = o[i] > 0.f ? o[i] : __expf(o[i]) - 1.f;  // ELU
    h8_t pk;
    #pragma unroll
    for (int i = 0; i < 8; ++i) pk[i] = (_Float16)o[i];
    *(h8_t*)&out[(size_t)d * 256 + coff] = pk;   // single 16B fp16 store
  }
}

// ======================= GATv2 aggregation, layer 2 (1 head, abs-trick, fused p) ======
__global__ __launch_bounds__(256) void gat_agg_l2(
    const half_t* __restrict__ xl0, const half_t* __restrict__ xr0,
    const float* __restrict__ att0, const float* __restrict__ bias0,
    float* __restrict__ out0,
    const half_t* __restrict__ xl1, const half_t* __restrict__ xr1,
    const float* __restrict__ att1, const float* __restrict__ bias1,
    const float* __restrict__ ll0, const float* __restrict__ lr0,
    const float* __restrict__ ll1, const float* __restrict__ lr1,
    const int* __restrict__ rowptr, const int* __restrict__ csr_src,
    const float* __restrict__ wp, float* __restrict__ pbuf,
    const int* __restrict__ order)
{
  constexpr int GRP = N_NODES / 4;
  int tid = threadIdx.x;
  int w = tid >> 6;
  int lane = tid & 63;
  int egrp = lane >> 3;
  int cch  = lane & 7;
  int bid = (int)blockIdx.x;
  int chain = bid >= GRP ? 1 : 0;
  int d = order[(bid - chain * GRP) * 4 + w];

  const half_t* xl = chain ? xl1 : xl0;
  const half_t* xr = chain ? xr1 : xr0;
  const float* att = chain ? att1 : att0;
  const float* bias = chain ? bias1 : bias0;
  const float* linl = chain ? ll1 : ll0;
  const float* linr = chain ? lr1 : lr0;

  int row0 = rowptr[d];
  int deg = rowptr[d + 1] - row0;
  int cbase = cch * 8;

  h2_t xr2[4], attA[4];
  {
    h8_t xv = *(const h8_t*)&xr[(unsigned)(d * 64 + cbase)];
    xr2[0] = h2_t{xv[0], xv[1]}; xr2[1] = h2_t{xv[2], xv[3]};
    xr2[2] = h2_t{xv[4], xv[5]}; xr2[3] = h2_t{xv[6], xv[7]};
    const float* atp = att + cbase;
    float4 b0 = *(const float4*)(atp);
    float4 b1 = *(const float4*)(atp + 4);
    attA[0] = h2_t{(_Float16)(0.4f * b0.x), (_Float16)(0.4f * b0.y)};
    attA[1] = h2_t{(_Float16)(0.4f * b0.z), (_Float16)(0.4f * b0.w)};
    attA[2] = h2_t{(_Float16)(0.4f * b1.x), (_Float16)(0.4f * b1.y)};
    attA[3] = h2_t{(_Float16)(0.4f * b1.z), (_Float16)(0.4f * b1.w)};
  }
  float linr_d = linr[d];

  auto ld_idx = [&](int k) -> int {
    int idx = k * 8 + egrp;
    int cl = idx < deg ? idx : (deg > 0 ? deg - 1 : 0);
    int pos = deg > 0 ? row0 + cl : 0;
    int sv = csr_src[pos];
    return idx < deg ? sv : d;
  };

  float zloc, a8[8];
  {
    h8_t xu = *(const h8_t*)&xl[(unsigned)(d * 64 + cbase)];
    float part = 0.f;
    #pragma unroll
    for (int j = 0; j < 4; ++j) {
      h2_t t = h2_t{xu[2 * j], xu[2 * j + 1]} + xr2[j];
      part = dot2h(abs_h2(t), attA[j], part);
    }
    part += __shfl_xor(part, 1, 64);
    part += __shfl_xor(part, 2, 64);
    part += __shfl_xor(part, 4, 64);
    part += linl[d] + linr_d;
    float wgt = __expf(part);
    float ws = (egrp == 0) ? wgt : 0.f;
    zloc = ws;
    #pragma unroll
    for (int i = 0; i < 8; ++i) a8[i] = (float)xu[i] * ws;
  }

  int C = (deg + 7) >> 3;
  int s_cur = ld_idx(0);
  h8_t xu_cur = *(const h8_t*)&xl[(unsigned)(s_cur * 64 + cbase)];
  float lin_cur = linl[s_cur];
  int s_nxt = ld_idx(1);
  for (int k = 0; k < C; ++k) {
    h8_t xu_nxt = *(const h8_t*)&xl[(unsigned)(s_nxt * 64 + cbase)];
    float lin_nxt = linl[s_nxt];
    int s_n2 = ld_idx(k + 2);
    bool valid = (k * 8 + egrp) < deg;
    float part = 0.f;
    #pragma unroll
    for (int j = 0; j < 4; ++j) {
      h2_t t = h2_t{xu_cur[2 * j], xu_cur[2 * j + 1]} + xr2[j];
      part = dot2h(abs_h2(t), attA[j], part);
    }
    part += __shfl_xor(part, 1, 64);
    part += __shfl_xor(part, 2, 64);
    part += __shfl_xor(part, 4, 64);
    part += lin_cur + linr_d;
    float wgt = valid ? __expf(part) : 0.f;
    zloc += wgt;
    #pragma unroll
    for (int i = 0; i < 8; ++i) a8[i] = fmaf((float)xu_cur[i], wgt, a8[i]);
    xu_cur = xu_nxt; lin_cur = lin_nxt; s_nxt = s_n2;
  }

  #pragma unroll
  for (int off = 8; off < 64; off <<= 1) {
    zloc += __shfl_xor(zloc, off, 64);
    #pragma unroll
    for (int i = 0; i < 8; ++i) a8[i] += __shfl_xor(a8[i], off, 64);
  }

  float invz = 1.f / zloc;
  float o[8];
  #pragma unroll
  for (int i = 0; i < 8; ++i) o[i] = a8[i] * invz + bias[cbase + i];

  if (chain) {
    // fold directly into CRF pairwise message p = (out) @ wp
    float p0 = 0.f, p1 = 0.f;
    #pragma unroll
    for (int i = 0; i < 8; ++i) {
      float2 wv = *(const float2*)&wp[(cbase + i) * 2];
      p0 = fmaf(o[i], wv.x, p0);
      p1 = fmaf(o[i], wv.y, p1);
    }
    p0 += __shfl_xor(p0, 1, 64); p1 += __shfl_xor(p1, 1, 64);
    p0 += __shfl_xor(p0, 2, 64); p1 += __shfl_xor(p1, 2, 64);
    p0 += __shfl_xor(p0, 4, 64); p1 += __shfl_xor(p1, 4, 64);
    if (lane == 0) *(float2*)&pbuf[2 * d] = make_float2(p0, p1);
  } else if (egrp == 0) {
    float* op = out0 + (size_t)d * 64 + cbase;
    *(float4*)(op)     = make_float4(o[0], o[1], o[2], o[3]);
    *(float4*)(op + 4) = make_float4(o[4], o[5], o[6], o[7]);
  }
}

// ======================= folded chunk kernel v8 (W in LDS, spill-free) ===============
__global__ __launch_bounds__(256) void chunk_fold_kernel(
    const float* __restrict__ A,
    const short* __restrict__ W1t,
    const float* __restrict__ b1,
    const float* __restrict__ WcT,
    const float* __restrict__ pc,
    float* __restrict__ pbufN,
    int Mtot)
{
  __shared__ short Ws[256 * 72];   // 36864 B, stride 72 shorts = bank-balanced for b128
  __shared__ float b1s[256];
  __shared__ float wcs[512];

  int tid = threadIdx.x;
  int w = tid >> 6;
  int lane = tid & 63;
  int quad = lane >> 4;
  int l15 = lane & 15;
  int row_base = (int)blockIdx.x * 256 + w * 64;

  // Phase 1: cooperative staging of W (32 KB) + tables into LDS.
  #pragma unroll
  for (int j = 0; j < 8; ++j) {
    int g = j * 256 + tid;
    int row = g >> 3, c = g & 7;
    *(int4*)&Ws[row * 72 + c * 8] = *(const int4*)&W1t[(size_t)g * 8];
  }
  b1s[tid] = b1[tid];
  wcs[tid] = WcT[tid];
  wcs[256 + tid] = WcT[256 + tid];
  __syncthreads();

  // Phase 2: A load + convert (no liveness across the barrier)
  bf8_t a1[4][2];
  #pragma unroll
  for (int rt = 0; rt < 4; ++rt) {
    int r = row_base + rt * 16 + l15;
    int rc = r < Mtot ? r : Mtot - 1;
    const float* ap = A + (size_t)rc * 64 + quad * 8;
    #pragma unroll
    for (int ks = 0; ks < 2; ++ks) {
      float4 v0 = *(const float4*)(ap + ks * 32);
      float4 v1 = *(const float4*)(ap + ks * 32 + 4);
      bf8_t f;
      f[0] = f2bf(v0.x); f[1] = f2bf(v0.y); f[2] = f2bf(v0.z); f[3] = f2bf(v0.w);
      f[4] = f2bf(v1.x); f[5] = f2bf(v1.y); f[6] = f2bf(v1.z); f[7] = f2bf(v1.w);
      a1[rt][ks] = f;
    }
  }

  float p0[4] = {0.f, 0.f, 0.f, 0.f};
  float p1[4] = {0.f, 0.f, 0.f, 0.f};

  // Phase 3: 16-iteration loop, LDS + registers only.
  #pragma unroll
  for (int i = 0; i < 16; ++i) {
    const short* wl = &Ws[(i * 16 + l15) * 72 + quad * 8];
    bf8_t w0 = *(const bf8_t*)(wl);
    bf8_t w1 = *(const bf8_t*)(wl + 32);

    f4_t g[4];
    #pragma unroll
    for (int rt = 0; rt < 4; ++rt) {
      f4_t z = {0.f, 0.f, 0.f, 0.f};
      z = __builtin_amdgcn_mfma_f32_16x16x32_bf16(w0, a1[rt][0], z, 0, 0, 0);
      z = __builtin_amdgcn_mfma_f32_16x16x32_bf16(w1, a1[rt][1], z, 0, 0, 0);
      g[rt] = z;
    }
    int cbase = i * 16 + quad * 4;
    f4_t b4  = *(const f4_t*)&b1s[cbase];
    f4_t wc0 = *(const f4_t*)&wcs[cbase];
    f4_t wc1 = *(const f4_t*)&wcs[256 + cbase];
    #pragma unroll
    for (int rt = 0; rt < 4; ++rt) {
      #pragma unroll
      for (int r = 0; r < 4; ++r) {
        float v = g[rt][r] + b4[r];
        v = v > 0.f ? v : __expf(v) - 1.f;
        p0[rt] = fmaf(v, wc0[r], p0[rt]);
        p1[rt] = fmaf(v, wc1[r], p1[rt]);
      }
    }
  }

  #pragma unroll
  for (int off = 16; off < 64; off <<= 1) {
    #pragma unroll
    for (int rt = 0; rt < 4; ++rt) {
      p0[rt] += __shfl_xor(p0[rt], off, 64);
      p1[rt] += __shfl_xor(p1[rt], off, 64);
    }
  }
  if (quad == 0) {
    float c0 = pc[0], c1 = pc[1];
    #pragma unroll
    for (int rt = 0; rt < 4; ++rt) {
      int row = row_base + rt * 16 + l15;
      if (row < Mtot)
        *(float2*)&pbufN[2 * row] = make_float2(p0[rt] + c0, p1[rt] + c1);
    }
  }
}

// ======================= Heads =======================
__global__ void head_kernel(const float* __restrict__ node_repr, const float* __restrict__ ph,
                            const int* __restrict__ rowptr, const int* __restrict__ csr_eid,
                            const float* __restrict__ pbuf, const float* __restrict__ wu,
                            const float* __restrict__ bu, const float* __restrict__ w2,
                            const float* __restrict__ b2, float* __restrict__ out, int n) {
  __shared__ float swu[128];
  __shared__ float sw2[256];
  int tid = threadIdx.x;
  if (tid < 128) swu[tid] = wu[tid];
  sw2[tid] = w2[tid];
  __syncthreads();
  int i = blockIdx.x * blockDim.x + tid;
  if (i >= n) return;
  float m0 = 0.f, m1 = 0.f;
  int r0 = rowptr[i], r1 = rowptr[i + 1];
  int jj = r0;
  for (; jj + 4 <= r1; jj += 4) {
    int e0 = csr_eid[jj + 0], e1 = csr_eid[jj + 1];
    int e2 = csr_eid[jj + 2], e3 = csr_eid[jj + 3];
    float2 q0 = *(const float2*)&pbuf[2 * e0];
    float2 q1 = *(const float2*)&pbuf[2 * e1];
    float2 q2 = *(const float2*)&pbuf[2 * e2];
    float2 q3 = *(const float2*)&pbuf[2 * e3];
    m0 += (q0.x + q1.x) + (q2.x + q3.x);
    m1 += (q0.y + q1.y) + (q2.y + q3.y);
  }
  for (; jj < r1; ++jj) {
    int e = csr_eid[jj];
    float2 q = *(const float2*)&pbuf[2 * e];
    m0 += q.x; m1 += q.y;
  }
  const float* nr = node_repr + (size_t)i * 64;
  float u0 = bu[0], u1 = bu[1];
  #pragma unroll
  for (int k = 0; k < 64; ++k) {
    float v = nr[k];
    u0 = fmaf(v, swu[2 * k + 0], u0);
    u1 = fmaf(v, swu[2 * k + 1], u1);
  }
  float v0 = u0 + m0;
  float v1 = u1 + m1;
  float mx = fmaxf(v0, v1);
  float lse = mx + logf(__expf(v0 - mx) + __expf(v1 - mx));
  out[2 * i + 0] = v0 - lse;
  out[2 * i + 1] = v1 - lse;
  const float* p = ph + (size_t)i * 128;
  float p0 = b2[0], p1 = b2[1];
  #pragma unroll
  for (int k = 0; k < 128; ++k) {
    float v = p[k];
    p0 = fmaf(v, sw2[2 * k + 0], p0);
    p1 = fmaf(v, sw2[2 * k + 1], p1);
  }
  out[2 * n + 2 * i + 0] = p0;
  out[2 * n + 2 * i + 1] = p1;
}

// ======================= launch =======================
extern "C" void kernel_launch(void* const* d_in, const int* in_sizes, int n_in,
                              void* d_out, int out_size, void* d_ws, size_t ws_size,
                              hipStream_t stream) {
  const int N = N_NODES, E = N_EDGES;
  const float* x         = (const float*)d_in[0];
  const float* edge_type = (const float*)d_in[1];
  const int*   ei        = (const int*)d_in[2];
  const float* n1_wl  = (const float*)d_in[3];
  const float* n1_wr  = (const float*)d_in[4];
  const float* n1_att = (const float*)d_in[5];
  const float* n1_b   = (const float*)d_in[6];
  const float* n2_wl  = (const float*)d_in[7];
  const float* n2_wr  = (const float*)d_in[8];
  const float* n2_att = (const float*)d_in[9];
  const float* n2_b   = (const float*)d_in[10];
  const float* e1_wl  = (const float*)d_in[11];
  const float* e1_wr  = (const float*)d_in[12];
  const float* e1_att = (const float*)d_in[13];
  const float* e1_b   = (const float*)d_in[14];
  const float* e2_wl  = (const float*)d_in[15];
  const float* e2_wr  = (const float*)d_in[16];
  const float* e2_att = (const float*)d_in[17];
  const float* e2_b   = (const float*)d_in[18];
  const float* crf_wu = (const float*)d_in[19];
  const float* crf_bu = (const float*)d_in[20];
  const float* crf_wp = (const float*)d_in[21];
  const float* px_w1  = (const float*)d_in[22];
  const float* px_b1  = (const float*)d_in[23];
  const float* px_w2  = (const float*)d_in[24];
  const float* px_b2  = (const float*)d_in[25];
  float* out = (float*)d_out;
  const int* src = ei;
  const int* dst = ei + E;
  (void)in_sizes; (void)n_in; (void)out_size; (void)ws_size;

  // ---- workspace layout (byte-identical footprint to the verified 452 µs kernel) ----
  char* ws = (char*)d_ws;
  size_t off = 0;
  auto alloc = [&](size_t bytes) -> void* {
    void* p = ws + off;
    off += (bytes + 255) & ~(size_t)255;
    return p;
  };
  half_t* xl_n  = (half_t*)alloc((size_t)N * 256 * 2);
  half_t* xr_n  = (half_t*)alloc((size_t)N * 256 * 2);
  half_t* xl_e  = (half_t*)alloc((size_t)N * 256 * 2);
  half_t* xr_e  = (half_t*)alloc((size_t)N * 256 * 2);
  // h_n / g_e stored as fp16 (allocations keep fp32 sizes -> layout unchanged)
  half_t* h_n  = (half_t*)alloc((size_t)N * 256 * 4);
  half_t* g_e  = (half_t*)alloc((size_t)N * 256 * 4);
  half_t* xl2_n = (half_t*)alloc((size_t)N * 64 * 2);
  half_t* xr2_n = (half_t*)alloc((size_t)N * 64 * 2);
  half_t* xl2_e = (half_t*)alloc((size_t)N * 64 * 2);
  half_t* xr2_e = (half_t*)alloc((size_t)N * 64 * 2);
  float* B3    = (float*)alloc((size_t)N * 64 * 4);
  float* pbuf  = (float*)alloc((size_t)E * 2 * 4);
  float* ph    = (float*)(void*)xl_n;   // reuse 10.24 MB
  int* deg     = (int*)alloc((size_t)N * 4);
  int* rowptr  = (int*)alloc((size_t)(N + 1) * 4);
  int* cursor  = (int*)alloc((size_t)N * 4);
  int* csr_src = (int*)alloc((size_t)E * 4);
  int* csr_eid = (int*)alloc((size_t)E * 4);
  short* t_n1l = (short*)alloc((size_t)16384 * 2);
  short* t_n1r = (short*)alloc((size_t)16384 * 2);
  short* t_e1l = (short*)alloc((size_t)16384 * 2);
  short* t_e1r = (short*)alloc((size_t)16384 * 2);
  short* t_n2l = (short*)alloc((size_t)16384 * 2);
  short* t_n2r = (short*)alloc((size_t)16384 * 2);
  short* t_e2l = (short*)alloc((size_t)16384 * 2);
  short* t_e2r = (short*)alloc((size_t)16384 * 2);
  float* WcT   = (float*)alloc((size_t)2 * 256 * 4);
  float* pcv   = (float*)alloc((size_t)2 * 4);
  // layer-1 linear-logit buffers aliased into pbuf (lifetime-disjoint, see r2 notes)
  float* l1ln = pbuf;
  float* l1rn = pbuf + 80000;
  float* l1le = pbuf + 160000;
  float* l1re = pbuf + 240000;
  // layer-2 linear-logit buffers aliased into xr_n (dead after gat_agg_l1)
  float* l2base = (float*)(void*)xr_n;
  float* l2ln = l2base;
  float* l2rn = l2base + 20000;
  float* l2le = l2base + 40000;
  float* l2re = l2base + 60000;
  // degree-sort scratch: hist/hcur (4 KB) alias head of B3 (first written by l2_agg,
  // long after the sort); order aliases cursor (dead after fill_csr).
  int* hist  = (int*)(void*)B3;
  int* hcur  = hist + 512;
  int* order = cursor;

  const int EB = (E + 255) / 256;
  const int NB = (N + 127) / 128;
  const int PB = (N + 63) / 64;
  const int NB256 = (N + 255) / 256;
  const int Mhigh = E - N;
  const int CFB = (Mhigh + 255) / 256;   // 256-row 4-wave blocks
  const int GRP = N / 4;

  hipMemsetAsync(deg, 0, (size_t)N * 4, stream);
  hipMemsetAsync(hist, 0, 512 * 4, stream);
  count_deg_kernel<<<EB, 256, 0, stream>>>(dst, deg, E);
  scan_kernel<<<1, 1024, 0, stream>>>(deg, rowptr, cursor, N);
  fill_csr_kernel<<<EB, 256, 0, stream>>>(src, dst, cursor, csr_src, csr_eid, E);
  // degree-descending node order for balanced aggregation blocks
  deg_hist_kernel<<<NB256, 256, 0, stream>>>(deg, hist, N);
  hist_scan_kernel<<<1, 512, 0, stream>>>(hist, hcur);
  order_scatter_kernel<<<NB256, 256, 0, stream>>>(deg, hcur, order, N);
  prep_all_kernel<<<515, 256, 0, stream>>>(n1_wl, n1_wr, e1_wl, e1_wr,
                                           n2_wl, n2_wr, e2_wl, e2_wr,
                                           e2_b, crf_wp,
                                           t_n1l, t_n1r, t_e1l, t_e1r,
                                           t_n2l, t_n2r, t_e2l, t_e2r, WcT, pcv);

  // ---- layer 1 ----
  mfma_proj2_kernel<64, float><<<dim3(PB, 8, 2), 128, 0, stream>>>(
      x, t_n1l, t_n1r, xl_n, xr_n,
      edge_type, t_e1l, t_e1r, xl_e, xr_e,
      n1_att, e1_att, l1ln, l1rn, l1le, l1re, N, 4);
  gat_agg_l1<<<2 * GRP, 256, 0, stream>>>(
      xl_n, xr_n, n1_att, n1_b, h_n,
      xl_e, xr_e, e1_att, e1_b, g_e,
      l1ln, l1rn, l1le, l1re, rowptr, csr_src, order);

  // ---- layer 2 ----
  mfma_proj2_kernel<256, half_t><<<dim3(PB, 2, 2), 128, 0, stream>>>(
      h_n, t_n2l, t_n2r, xl2_n, xr2_n,
      g_e, t_e2l, t_e2r, xl2_e, xr2_e,
      n2_att, e2_att, l2ln, l2rn, l2le, l2re, N, 1);
  gat_agg_l2<<<2 * GRP, 256, 0, stream>>>(
      xl2_n, xr2_n, n2_att, n2_b, B3,
      xl2_e, xr2_e, e2_att, e2_b,
      l2ln, l2rn, l2le, l2re, rowptr, csr_src, crf_wp, pbuf, order);

  // ---- CRF p for self-loop-only edge rows ----
  chunk_fold_kernel<<<CFB, 256, 0, stream>>>(edge_type + (size_t)N * 64, t_e1l,
                                             e1_b, WcT, pcv, pbuf + 2 * (size_t)N, Mhigh);

  // ---- heads ----
  gemm64_kernel<64, 3><<<dim3(NB, 2), 256, 0, stream>>>(B3, px_w1, 128, px_b1, ph, 128, N);
  head_kernel<<<(N + 255) / 256, 256, 0, stream>>>(B3, ph, rowptr, csr_eid, pbuf,
                                                   crf_wu, crf_bu, px_w2, px_b2, out, N);
}

// Round 11
// 407.666 us; speedup vs baseline: 1.2636x; 1.2636x over previous
//
#include <hip/hip_runtime.h>
#include <cstddef>
#include <cstdint>

#define N_NODES 20000
#define N_EDGES 320000

typedef __attribute__((ext_vector_type(8))) short bf8_t;   // 8 x bf16 (MFMA frag)
typedef __attribute__((ext_vector_type(4))) float f4_t;    // MFMA acc / float4
typedef __attribute__((ext_vector_type(2))) float f2_t;
typedef unsigned short bfu;
typedef _Float16 half_t;
typedef __attribute__((ext_vector_type(2))) _Float16 h2_t;
typedef __attribute__((ext_vector_type(4))) _Float16 h4_t;
typedef __attribute__((ext_vector_type(8))) _Float16 h8_t;

__device__ __forceinline__ short f2bf(float f) {
  unsigned u = __float_as_uint(f);
  u += 0x7fff + ((u >> 16) & 1);   // round-to-nearest-even
  return (short)(u >> 16);
}
// |t| on packed f16 (clear sign bits)
__device__ __forceinline__ h2_t abs_h2(h2_t t) {
  unsigned u = __builtin_bit_cast(unsigned, t) & 0x7fff7fffu;
  return __builtin_bit_cast(h2_t, u);
}
__device__ __forceinline__ float dot2h(h2_t a, h2_t b, float c) {
#if __has_builtin(__builtin_amdgcn_fdot2)
  return __builtin_amdgcn_fdot2(a, b, c, false);
#else
  return c + (float)a.x * (float)b.x + (float)a.y * (float)b.y;
#endif
}

// ======================= CSR build =======================
__global__ void count_deg_kernel(const int* __restrict__ dst, int* __restrict__ deg, int e_cnt) {
  int e = blockIdx.x * blockDim.x + threadIdx.x;
  if (e < e_cnt) atomicAdd(&deg[dst[e]], 1);
}

__global__ __launch_bounds__(1024) void scan_kernel(
    const int* __restrict__ deg, int* __restrict__ rowptr,
    int* __restrict__ cursor, int n) {
  __shared__ int sdata[1024];
  constexpr int CH = (N_NODES + 1023) / 1024;   // compile-time -> loc[] stays in regs
  int tid = threadIdx.x;
  int base = tid * CH;
  int loc[CH];
  int s = 0;
  #pragma unroll
  for (int j = 0; j < CH; ++j) {
    int idx = base + j;
    int v = (idx < n) ? deg[idx] : 0;
    loc[j] = s;
    s += v;
  }
  sdata[tid] = s;
  __syncthreads();
  for (int off = 1; off < 1024; off <<= 1) {
    int t = (tid >= off) ? sdata[tid - off] : 0;
    __syncthreads();
    sdata[tid] += t;
    __syncthreads();
  }
  int excl = sdata[tid] - s;
  #pragma unroll
  for (int j = 0; j < CH; ++j) {
    int idx = base + j;
    if (idx < n) { int val = excl + loc[j]; rowptr[idx] = val; cursor[idx] = val; }
  }
  if (tid == 0) rowptr[n] = sdata[1023];
}

__global__ void fill_csr_kernel(const int* __restrict__ src, const int* __restrict__ dst,
                                int* __restrict__ cursor, int* __restrict__ csr_src,
                                int* __restrict__ csr_eid, int e_cnt) {
  int e = blockIdx.x * blockDim.x + threadIdx.x;
  if (e < e_cnt) {
    int pos = atomicAdd(&cursor[dst[e]], 1);
    csr_src[pos] = src[e];
    csr_eid[pos] = e;
  }
}

// ======================= degree-sorted node order (load balancing) ===================
// Round-10 post-mortem: flat per-thread global atomics serialized on hot degree bins
// (54 us each at 0.009% VALUBusy). v2 is hierarchical: LDS histogram per block, then
// <=512 global atomics per block SPREAD across 512 addresses; scatter reserves one
// contiguous range per (block,bin) with a single global atomic and ranks within the
// block via LDS atomics (guideline 12).
__global__ __launch_bounds__(256) void deg_hist_kernel(
    const int* __restrict__ deg, int* __restrict__ hist, int n) {
  __shared__ int lh[512];
  int tid = threadIdx.x;
  lh[tid] = 0; lh[tid + 256] = 0;
  __syncthreads();
  int i = blockIdx.x * 256 + tid;
  if (i < n) {
    int b = deg[i]; b = b > 511 ? 511 : b;
    atomicAdd(&lh[511 - b], 1);          // LDS atomic (reversed bins -> descending)
  }
  __syncthreads();
  if (lh[tid])       atomicAdd(&hist[tid],       lh[tid]);
  if (lh[tid + 256]) atomicAdd(&hist[tid + 256], lh[tid + 256]);
}

__global__ __launch_bounds__(512) void hist_scan_kernel(
    const int* __restrict__ hist, int* __restrict__ hcur) {
  __shared__ int s[512];
  int t = threadIdx.x;
  s[t] = hist[t];
  __syncthreads();
  for (int off = 1; off < 512; off <<= 1) {
    int v = (t >= off) ? s[t - off] : 0;
    __syncthreads();
    s[t] += v;
    __syncthreads();
  }
  hcur[t] = s[t] - hist[t];   // exclusive prefix
}

__global__ __launch_bounds__(256) void order_scatter_kernel(
    const int* __restrict__ deg, int* __restrict__ hcur,
    int* __restrict__ order, int n) {
  __shared__ int lh[512], lbase[512], lcur[512];
  int tid = threadIdx.x;
  lh[tid] = 0; lh[tid + 256] = 0;
  lcur[tid] = 0; lcur[tid + 256] = 0;
  __syncthreads();
  int i = blockIdx.x * 256 + tid;
  int rb = -1;
  if (i < n) {
    int b = deg[i]; b = b > 511 ? 511 : b;
    rb = 511 - b;
    atomicAdd(&lh[rb], 1);               // LDS atomic: count per (block,bin)
  }
  __syncthreads();
  if (lh[tid])       lbase[tid]       = atomicAdd(&hcur[tid],       lh[tid]);
  if (lh[tid + 256]) lbase[tid + 256] = atomicAdd(&hcur[tid + 256], lh[tid + 256]);
  __syncthreads();
  if (i < n) {
    int r = atomicAdd(&lcur[rb], 1);     // LDS atomic: rank within (block,bin)
    order[lbase[rb] + r] = i;
  }
}

// ======================= weight prep =======================
__global__ void prep_all_kernel(
    const float* __restrict__ n1l, const float* __restrict__ n1r,
    const float* __restrict__ e1l, const float* __restrict__ e1r,
    const float* __restrict__ n2l, const float* __restrict__ n2r,
    const float* __restrict__ e2l, const float* __restrict__ e2r,
    const float* __restrict__ b2, const float* __restrict__ wp,
    short* __restrict__ t_n1l, short* __restrict__ t_n1r,
    short* __restrict__ t_e1l, short* __restrict__ t_e1r,
    short* __restrict__ t_n2l, short* __restrict__ t_n2r,
    short* __restrict__ t_e2l, short* __restrict__ t_e2r,
    float* __restrict__ wct, float* __restrict__ pc)
{
  int i = blockIdx.x * blockDim.x + threadIdx.x;
  int seg = i >> 14;
  int j = i & 16383;
  if (seg < 4) {
    const float* srcs[4] = {n1l, n1r, e1l, e1r};
    short* dsts[4] = {t_n1l, t_n1r, t_e1l, t_e1r};
    int n = j >> 6, k = j & 63;
    dsts[seg][n * 64 + k] = f2bf(srcs[seg][k * 256 + n]);
  } else if (seg < 8) {
    const float* srcs[4] = {n2l, n2r, e2l, e2r};
    short* dsts[4] = {t_n2l, t_n2r, t_e2l, t_e2r};
    int n = j >> 8, k = j & 255;
    dsts[seg - 4][n * 256 + k] = f2bf(srcs[seg - 4][k * 64 + n]);
  } else if (seg == 8) {
    if (j < 512) {
      int jj = j & 1;
      int k  = j >> 1;
      float s = 0.f;
      for (int c = 0; c < 64; ++c) s = fmaf(e2l[k * 64 + c], wp[c * 2 + jj], s);
      wct[jj * 256 + k] = s;
    } else if (j < 514) {
      int jj = j - 512;
      float s = 0.f;
      for (int c = 0; c < 64; ++c) s = fmaf(b2[c], wp[c * 2 + jj], s);
      pc[jj] = s;
    }
  }
}

// ======================= MFMA projection kernel (dual-chain, fp16 outputs) ==========
template<int K, typename SrcT>
__global__ __launch_bounds__(128) void mfma_proj2_kernel(
    const SrcT* __restrict__ A0,
    const short* __restrict__ Wtl0, const short* __restrict__ Wtr0,
    half_t* __restrict__ xl0, half_t* __restrict__ xr0,
    const SrcT* __restrict__ A1,
    const short* __restrict__ Wtl1, const short* __restrict__ Wtr1,
    half_t* __restrict__ xl1, half_t* __restrict__ xr1,
    const float* __restrict__ att0, const float* __restrict__ att1,
    float* __restrict__ ll0, float* __restrict__ lr0,
    float* __restrict__ ll1, float* __restrict__ lr1,
    int M, int nslices)
{
  constexpr int KC = K / 32;
  int tid = threadIdx.x;
  int w = tid >> 6, lane = tid & 63, quad = lane >> 4, l15 = lane & 15;
  int row_base = (int)blockIdx.x * 64 + w * 32;
  int y = (int)blockIdx.y;
  int z = (int)blockIdx.z;
  const SrcT* A = z ? A1 : A0;
  bool is_l = y < nslices;
  const short* Wt = z ? (is_l ? Wtl1 : Wtr1) : (is_l ? Wtl0 : Wtr0);
  half_t* dst = z ? (is_l ? xl1 : xr1) : (is_l ? xl0 : xr0);
  const float* att = z ? att1 : att0;
  float* lin = z ? (is_l ? ll1 : lr1) : (is_l ? ll0 : lr0);
  int head = is_l ? y : y - nslices;
  int cb = head * 64;
  const float* atp = att + head * 64;
  int STR = nslices * 64;

  bf8_t a[2][KC];
  #pragma unroll
  for (int rt = 0; rt < 2; ++rt) {
    int r = row_base + rt * 16 + l15;
    int rc = r < M ? r : M - 1;
    const SrcT* ap = A + (size_t)rc * K + quad * 8;
    #pragma unroll
    for (int kc = 0; kc < KC; ++kc) {
      bf8_t f;
      if constexpr (sizeof(SrcT) == 4) {
        float4 v0 = *(const float4*)(ap + kc * 32);
        float4 v1 = *(const float4*)(ap + kc * 32 + 4);
        f[0] = f2bf(v0.x); f[1] = f2bf(v0.y); f[2] = f2bf(v0.z); f[3] = f2bf(v0.w);
        f[4] = f2bf(v1.x); f[5] = f2bf(v1.y); f[6] = f2bf(v1.z); f[7] = f2bf(v1.w);
      } else {
        h8_t hv = *(const h8_t*)(ap + kc * 32);
        #pragma unroll
        for (int q = 0; q < 8; ++q) f[q] = f2bf((float)hv[q]);
      }
      a[rt][kc] = f;
    }
  }

  float lacc0 = 0.f, lacc1 = 0.f;
  #pragma unroll
  for (int nt = 0; nt < 4; ++nt) {
    f4_t acc0 = {0.f, 0.f, 0.f, 0.f};
    f4_t acc1 = {0.f, 0.f, 0.f, 0.f};
    const short* wb = Wt + (size_t)(cb + nt * 16 + l15) * K + quad * 8;
    #pragma unroll
    for (int kc = 0; kc < KC; ++kc) {
      bf8_t wf = *(const bf8_t*)(wb + kc * 32);
      acc0 = __builtin_amdgcn_mfma_f32_16x16x32_bf16(wf, a[0][kc], acc0, 0, 0, 0);
      acc1 = __builtin_amdgcn_mfma_f32_16x16x32_bf16(wf, a[1][kc], acc1, 0, 0, 0);
    }
    // att-dot for the linear logit part (cols nt*16 + quad*4 + j of this head)
    f4_t av = *(const f4_t*)(atp + nt * 16 + quad * 4);
    lacc0 += acc0[0] * av[0] + acc0[1] * av[1] + acc0[2] * av[2] + acc0[3] * av[3];
    lacc1 += acc1[0] * av[0] + acc1[1] * av[1] + acc1[2] * av[2] + acc1[3] * av[3];
    #pragma unroll
    for (int rt = 0; rt < 2; ++rt) {
      f4_t acc = rt == 0 ? acc0 : acc1;
      int row = row_base + rt * 16 + l15;
      if (row >= M) continue;
      int col = cb + nt * 16 + quad * 4;
      h4_t pk;
      pk[0] = (_Float16)acc[0]; pk[1] = (_Float16)acc[1];
      pk[2] = (_Float16)acc[2]; pk[3] = (_Float16)acc[3];
      *(h4_t*)&dst[(size_t)row * STR + col] = pk;
    }
  }
  // reduce lacc across the 4 quads (each quad covered a disjoint col subset)
  lacc0 += __shfl_xor(lacc0, 16, 64); lacc0 += __shfl_xor(lacc0, 32, 64);
  lacc1 += __shfl_xor(lacc1, 16, 64); lacc1 += __shfl_xor(lacc1, 32, 64);
  if (quad == 0) {
    int r0 = row_base + l15;
    int r1 = row_base + 16 + l15;
    if (r0 < M) lin[(size_t)r0 * nslices + head] = 0.6f * lacc0;
    if (r1 < M) lin[(size_t)r1 * nslices + head] = 0.6f * lacc1;
  }
}

// ======================= fp32 GEMM (proxy head only) =======================
template<int KIN>
__device__ __forceinline__ void gemm_body(
    const float* __restrict__ A, const float* __restrict__ W, int wld, int cb,
    int block_m, int M, float (&acc)[8][4],
    float (*As)[128 + 4], float (*Ws)[64 + 4])
{
  int tid = threadIdx.x;
  int tx = tid & 15;
  int ty = tid >> 4;
  #pragma unroll
  for (int i = 0; i < 8; ++i)
    #pragma unroll
    for (int j = 0; j < 4; ++j) acc[i][j] = 0.f;

  for (int k0 = 0; k0 < KIN; k0 += 16) {
    #pragma unroll
    for (int rep = 0; rep < 2; ++rep) {
      int ar = (tid >> 2) + rep * 64;
      int ak = (tid & 3) * 4;
      int gr = block_m + ar;
      float4 v = make_float4(0.f, 0.f, 0.f, 0.f);
      if (gr < M) v = *(const float4*)&A[(size_t)gr * KIN + k0 + ak];
      As[ak + 0][ar] = v.x; As[ak + 1][ar] = v.y;
      As[ak + 2][ar] = v.z; As[ak + 3][ar] = v.w;
    }
    {
      int wr = tid >> 4;
      int wc = (tid & 15) * 4;
      float4 v = *(const float4*)&W[(size_t)(k0 + wr) * wld + cb + wc];
      Ws[wr][wc + 0] = v.x; Ws[wr][wc + 1] = v.y;
      Ws[wr][wc + 2] = v.z; Ws[wr][wc + 3] = v.w;
    }
    __syncthreads();
    #pragma unroll
    for (int k = 0; k < 16; ++k) {
      float a[8], w[4];
      #pragma unroll
      for (int i = 0; i < 8; ++i) a[i] = As[k][ty * 8 + i];
      #pragma unroll
      for (int j = 0; j < 4; ++j) w[j] = Ws[k][tx * 4 + j];
      #pragma unroll
      for (int i = 0; i < 8; ++i)
        #pragma unroll
        for (int j = 0; j < 4; ++j) acc[i][j] = fmaf(a[i], w[j], acc[i][j]);
    }
    __syncthreads();
  }
}

template<int KIN, int MODE>
__global__ __launch_bounds__(256) void gemm64_kernel(
    const float* __restrict__ A, const float* __restrict__ W, int wld,
    const float* __restrict__ bias, float* __restrict__ out, int old, int M)
{
  __shared__ float As[16][128 + 4];
  __shared__ float Ws[16][64 + 4];
  float acc[8][4];
  int block_m = (int)blockIdx.x * 128;
  int cb = (int)blockIdx.y * 64;
  gemm_body<KIN>(A, W, wld, cb, block_m, M, acc, As, Ws);

  int tid = threadIdx.x;
  int tx = tid & 15, ty = tid >> 4;
  int gc = cb + tx * 4;
  #pragma unroll
  for (int i = 0; i < 8; ++i) {
    int gr = block_m + ty * 8 + i;
    if (gr >= M) continue;
    size_t idx = (size_t)gr * old + gc;
    float t0 = acc[i][0], t1 = acc[i][1], t2 = acc[i][2], t3 = acc[i][3];
    if (MODE == 3) {
      t0 = fmaxf(t0 + bias[gc + 0], 0.f);
      t1 = fmaxf(t1 + bias[gc + 1], 0.f);
      t2 = fmaxf(t2 + bias[gc + 2], 0.f);
      t3 = fmaxf(t3 + bias[gc + 3], 0.f);
    }
    *(float4*)&out[idx] = make_float4(t0, t1, t2, t3);
  }
}

// ======================= GATv2 aggregation, layer 1 (4 heads fused per wave) ==========
// Waves take d = order[...] (degree-sorted) so the 4 sibling waves of a block have
// near-equal trip counts — block retires at max(sibling degrees).
__global__ __launch_bounds__(256) void gat_agg_l1(
    const half_t* __restrict__ xl0, const half_t* __restrict__ xr0,
    const float* __restrict__ att0, const float* __restrict__ bias0,
    half_t* __restrict__ out0,
    const half_t* __restrict__ xl1, const half_t* __restrict__ xr1,
    const float* __restrict__ att1, const float* __restrict__ bias1,
    half_t* __restrict__ out1,
    const float* __restrict__ ll0, const float* __restrict__ lr0,
    const float* __restrict__ ll1, const float* __restrict__ lr1,
    const int* __restrict__ rowptr, const int* __restrict__ csr_src,
    const int* __restrict__ order)
{
  constexpr int GRP = N_NODES / 4;
  int tid = threadIdx.x;
  int w = tid >> 6, lane = tid & 63;
  int egrp = lane >> 5;
  int head = (lane >> 3) & 3;
  int coff = (lane & 31) * 8;
  int bid = (int)blockIdx.x;
  int chain = bid >= GRP ? 1 : 0;
  int d = order[(bid - chain * GRP) * 4 + w];

  const half_t* xl = chain ? xl1 : xl0;
  const half_t* xr = chain ? xr1 : xr0;
  const float* att = chain ? att1 : att0;
  const float* bias = chain ? bias1 : bias0;
  const float* linl = chain ? ll1 : ll0;
  const float* linr = chain ? lr1 : lr0;
  half_t* out = chain ? out1 : out0;

  int row0 = rowptr[d];
  int deg = rowptr[d + 1] - row0;

  h2_t xr2[4], attA[4];
  {
    h8_t xv = *(const h8_t*)&xr[(unsigned)(d * 256 + coff)];
    xr2[0] = h2_t{xv[0], xv[1]}; xr2[1] = h2_t{xv[2], xv[3]};
    xr2[2] = h2_t{xv[4], xv[5]}; xr2[3] = h2_t{xv[6], xv[7]};
    const float* atp = att + coff;
    float4 b0 = *(const float4*)(atp);
    float4 b1 = *(const float4*)(atp + 4);
    attA[0] = h2_t{(_Float16)(0.4f * b0.x), (_Float16)(0.4f * b0.y)};
    attA[1] = h2_t{(_Float16)(0.4f * b0.z), (_Float16)(0.4f * b0.w)};
    attA[2] = h2_t{(_Float16)(0.4f * b1.x), (_Float16)(0.4f * b1.y)};
    attA[3] = h2_t{(_Float16)(0.4f * b1.z), (_Float16)(0.4f * b1.w)};
  }
  float linr_d = linr[(unsigned)(d * 4 + head)];

  auto ld_idx = [&](int k) -> int {
    int idx = k * 2 + egrp;
    int cl = idx < deg ? idx : (deg > 0 ? deg - 1 : 0);
    int pos = deg > 0 ? row0 + cl : 0;
    int sv = csr_src[pos];
    return idx < deg ? sv : d;
  };

  float zloc, a8[8];
  {
    // self loop (counted once via egrp==0 mask)
    h8_t xu = *(const h8_t*)&xl[(unsigned)(d * 256 + coff)];
    float part = 0.f;
    #pragma unroll
    for (int j = 0; j < 4; ++j) {
      h2_t t = h2_t{xu[2 * j], xu[2 * j + 1]} + xr2[j];
      part = dot2h(abs_h2(t), attA[j], part);
    }
    part += __shfl_xor(part, 1, 64);
    part += __shfl_xor(part, 2, 64);
    part += __shfl_xor(part, 4, 64);
    part += linl[(unsigned)(d * 4 + head)] + linr_d;
    float wgt = __expf(part);
    float ws = (egrp == 0) ? wgt : 0.f;
    zloc = ws;
    #pragma unroll
    for (int i = 0; i < 8; ++i) a8[i] = (float)xu[i] * ws;
  }

  int C = (deg + 1) >> 1;
  int s_cur = ld_idx(0);
  h8_t xu_cur = *(const h8_t*)&xl[(unsigned)(s_cur * 256 + coff)];
  float lin_cur = linl[(unsigned)(s_cur * 4 + head)];
  int s_nxt = ld_idx(1);
  for (int k = 0; k < C; ++k) {
    h8_t xu_nxt = *(const h8_t*)&xl[(unsigned)(s_nxt * 256 + coff)];
    float lin_nxt = linl[(unsigned)(s_nxt * 4 + head)];
    int s_n2 = ld_idx(k + 2);
    bool valid = (k * 2 + egrp) < deg;
    float part = 0.f;
    #pragma unroll
    for (int j = 0; j < 4; ++j) {
      h2_t t = h2_t{xu_cur[2 * j], xu_cur[2 * j + 1]} + xr2[j];
      part = dot2h(abs_h2(t), attA[j], part);
    }
    part += __shfl_xor(part, 1, 64);
    part += __shfl_xor(part, 2, 64);
    part += __shfl_xor(part, 4, 64);
    part += lin_cur + linr_d;
    float wgt = valid ? __expf(part) : 0.f;
    zloc += wgt;
    #pragma unroll
    for (int i = 0; i < 8; ++i) a8[i] = fmaf((float)xu_cur[i], wgt, a8[i]);
    xu_cur = xu_nxt; lin_cur = lin_nxt; s_nxt = s_n2;
  }

  // combine the two edge-slot halves
  zloc += __shfl_xor(zloc, 32, 64);
  #pragma unroll
  for (int i = 0; i < 8; ++i) a8[i] += __shfl_xor(a8[i], 32, 64);

  if (egrp == 0) {
    float invz = 1.f / zloc;
    const float* bp = bias + coff;
    float4 c0 = *(const float4*)(bp);
    float4 c1 = *(const float4*)(bp + 4);
    float o[8];
    o[0] = a8[0] * invz + c0.x; o[1] = a8[1] * invz + c0.y;
    o[2] = a8[2] * invz + c0.z; o[3] = a8[3] * invz + c0.w;
    o[4] = a8[4] * invz + c1.x; o[5] = a8[5] * invz + c1.y;
    o[6] = a8[6] * invz + c1.z; o[7] = a8[7] * invz + c1.w;
    #pragma unroll
    for (int i = 0; i < 8; ++i) o[i] = o[i] > 0.f ? o[i] : __expf(o[i]) - 1.f;  // ELU
    h8_t pk;
    #pragma unroll
    for (int i = 0; i < 8; ++i) pk[i] = (_Float16)o[i];
    *(h8_t*)&out[(size_t)d * 256 + coff] = pk;   // single 16B fp16 store
  }
}

// ======================= GATv2 aggregation, layer 2 (1 head, abs-trick, fused p) ======
__global__ __launch_bounds__(256) void gat_agg_l2(
    const half_t* __restrict__ xl0, const half_t* __restrict__ xr0,
    const float* __restrict__ att0, const float* __restrict__ bias0,
    float* __restrict__ out0,
    const half_t* __restrict__ xl1, const half_t* __restrict__ xr1,
    const float* __restrict__ att1, const float* __restrict__ bias1,
    const float* __restrict__ ll0, const float* __restrict__ lr0,
    const float* __restrict__ ll1, const float* __restrict__ lr1,
    const int* __restrict__ rowptr, const int* __restrict__ csr_src,
    const float* __restrict__ wp, float* __restrict__ pbuf,
    const int* __restrict__ order)
{
  constexpr int GRP = N_NODES / 4;
  int tid = threadIdx.x;
  int w = tid >> 6;
  int lane = tid & 63;
  int egrp = lane >> 3;
  int cch  = lane & 7;
  int bid = (int)blockIdx.x;
  int chain = bid >= GRP ? 1 : 0;
  int d = order[(bid - chain * GRP) * 4 + w];

  const half_t* xl = chain ? xl1 : xl0;
  const half_t* xr = chain ? xr1 : xr0;
  const float* att = chain ? att1 : att0;
  const float* bias = chain ? bias1 : bias0;
  const float* linl = chain ? ll1 : ll0;
  const float* linr = chain ? lr1 : lr0;

  int row0 = rowptr[d];
  int deg = rowptr[d + 1] - row0;
  int cbase = cch * 8;

  h2_t xr2[4], attA[4];
  {
    h8_t xv = *(const h8_t*)&xr[(unsigned)(d * 64 + cbase)];
    xr2[0] = h2_t{xv[0], xv[1]}; xr2[1] = h2_t{xv[2], xv[3]};
    xr2[2] = h2_t{xv[4], xv[5]}; xr2[3] = h2_t{xv[6], xv[7]};
    const float* atp = att + cbase;
    float4 b0 = *(const float4*)(atp);
    float4 b1 = *(const float4*)(atp + 4);
    attA[0] = h2_t{(_Float16)(0.4f * b0.x), (_Float16)(0.4f * b0.y)};
    attA[1] = h2_t{(_Float16)(0.4f * b0.z), (_Float16)(0.4f * b0.w)};
    attA[2] = h2_t{(_Float16)(0.4f * b1.x), (_Float16)(0.4f * b1.y)};
    attA[3] = h2_t{(_Float16)(0.4f * b1.z), (_Float16)(0.4f * b1.w)};
  }
  float linr_d = linr[d];

  auto ld_idx = [&](int k) -> int {
    int idx = k * 8 + egrp;
    int cl = idx < deg ? idx : (deg > 0 ? deg - 1 : 0);
    int pos = deg > 0 ? row0 + cl : 0;
    int sv = csr_src[pos];
    return idx < deg ? sv : d;
  };

  float zloc, a8[8];
  {
    h8_t xu = *(const h8_t*)&xl[(unsigned)(d * 64 + cbase)];
    float part = 0.f;
    #pragma unroll
    for (int j = 0; j < 4; ++j) {
      h2_t t = h2_t{xu[2 * j], xu[2 * j + 1]} + xr2[j];
      part = dot2h(abs_h2(t), attA[j], part);
    }
    part += __shfl_xor(part, 1, 64);
    part += __shfl_xor(part, 2, 64);
    part += __shfl_xor(part, 4, 64);
    part += linl[d] + linr_d;
    float wgt = __expf(part);
    float ws = (egrp == 0) ? wgt : 0.f;
    zloc = ws;
    #pragma unroll
    for (int i = 0; i < 8; ++i) a8[i] = (float)xu[i] * ws;
  }

  int C = (deg + 7) >> 3;
  int s_cur = ld_idx(0);
  h8_t xu_cur = *(const h8_t*)&xl[(unsigned)(s_cur * 64 + cbase)];
  float lin_cur = linl[s_cur];
  int s_nxt = ld_idx(1);
  for (int k = 0; k < C; ++k) {
    h8_t xu_nxt = *(const h8_t*)&xl[(unsigned)(s_nxt * 64 + cbase)];
    float lin_nxt = linl[s_nxt];
    int s_n2 = ld_idx(k + 2);
    bool valid = (k * 8 + egrp) < deg;
    float part = 0.f;
    #pragma unroll
    for (int j = 0; j < 4; ++j) {
      h2_t t = h2_t{xu_cur[2 * j], xu_cur[2 * j + 1]} + xr2[j];
      part = dot2h(abs_h2(t), attA[j], part);
    }
    part += __shfl_xor(part, 1, 64);
    part += __shfl_xor(part, 2, 64);
    part += __shfl_xor(part, 4, 64);
    part += lin_cur + linr_d;
    float wgt = valid ? __expf(part) : 0.f;
    zloc += wgt;
    #pragma unroll
    for (int i = 0; i < 8; ++i) a8[i] = fmaf((float)xu_cur[i], wgt, a8[i]);
    xu_cur = xu_nxt; lin_cur = lin_nxt; s_nxt = s_n2;
  }

  #pragma unroll
  for (int off = 8; off < 64; off <<= 1) {
    zloc += __shfl_xor(zloc, off, 64);
    #pragma unroll
    for (int i = 0; i < 8; ++i) a8[i] += __shfl_xor(a8[i], off, 64);
  }

  float invz = 1.f / zloc;
  float o[8];
  #pragma unroll
  for (int i = 0; i < 8; ++i) o[i] = a8[i] * invz + bias[cbase + i];

  if (chain) {
    // fold directly into CRF pairwise message p = (out) @ wp
    float p0 = 0.f, p1 = 0.f;
    #pragma unroll
    for (int i = 0; i < 8; ++i) {
      float2 wv = *(const float2*)&wp[(cbase + i) * 2];
      p0 = fmaf(o[i], wv.x, p0);
      p1 = fmaf(o[i], wv.y, p1);
    }
    p0 += __shfl_xor(p0, 1, 64); p1 += __shfl_xor(p1, 1, 64);
    p0 += __shfl_xor(p0, 2, 64); p1 += __shfl_xor(p1, 2, 64);
    p0 += __shfl_xor(p0, 4, 64); p1 += __shfl_xor(p1, 4, 64);
    if (lane == 0) *(float2*)&pbuf[2 * d] = make_float2(p0, p1);
  } else if (egrp == 0) {
    float* op = out0 + (size_t)d * 64 + cbase;
    *(float4*)(op)     = make_float4(o[0], o[1], o[2], o[3]);
    *(float4*)(op + 4) = make_float4(o[4], o[5], o[6], o[7]);
  }
}

// ======================= folded chunk kernel v8 (W in LDS, spill-free) ===============
__global__ __launch_bounds__(256) void chunk_fold_kernel(
    const float* __restrict__ A,
    const short* __restrict__ W1t,
    const float* __restrict__ b1,
    const float* __restrict__ WcT,
    const float* __restrict__ pc,
    float* __restrict__ pbufN,
    int Mtot)
{
  __shared__ short Ws[256 * 72];   // 36864 B, stride 72 shorts = bank-balanced for b128
  __shared__ float b1s[256];
  __shared__ float wcs[512];

  int tid = threadIdx.x;
  int w = tid >> 6;
  int lane = tid & 63;
  int quad = lane >> 4;
  int l15 = lane & 15;
  int row_base = (int)blockIdx.x * 256 + w * 64;

  // Phase 1: cooperative staging of W (32 KB) + tables into LDS.
  #pragma unroll
  for (int j = 0; j < 8; ++j) {
    int g = j * 256 + tid;
    int row = g >> 3, c = g & 7;
    *(int4*)&Ws[row * 72 + c * 8] = *(const int4*)&W1t[(size_t)g * 8];
  }
  b1s[tid] = b1[tid];
  wcs[tid] = WcT[tid];
  wcs[256 + tid] = WcT[256 + tid];
  __syncthreads();

  // Phase 2: A load + convert (no liveness across the barrier)
  bf8_t a1[4][2];
  #pragma unroll
  for (int rt = 0; rt < 4; ++rt) {
    int r = row_base + rt * 16 + l15;
    int rc = r < Mtot ? r : Mtot - 1;
    const float* ap = A + (size_t)rc * 64 + quad * 8;
    #pragma unroll
    for (int ks = 0; ks < 2; ++ks) {
      float4 v0 = *(const float4*)(ap + ks * 32);
      float4 v1 = *(const float4*)(ap + ks * 32 + 4);
      bf8_t f;
      f[0] = f2bf(v0.x); f[1] = f2bf(v0.y); f[2] = f2bf(v0.z); f[3] = f2bf(v0.w);
      f[4] = f2bf(v1.x); f[5] = f2bf(v1.y); f[6] = f2bf(v1.z); f[7] = f2bf(v1.w);
      a1[rt][ks] = f;
    }
  }

  float p0[4] = {0.f, 0.f, 0.f, 0.f};
  float p1[4] = {0.f, 0.f, 0.f, 0.f};

  // Phase 3: 16-iteration loop, LDS + registers only.
  #pragma unroll
  for (int i = 0; i < 16; ++i) {
    const short* wl = &Ws[(i * 16 + l15) * 72 + quad * 8];
    bf8_t w0 = *(const bf8_t*)(wl);
    bf8_t w1 = *(const bf8_t*)(wl + 32);

    f4_t g[4];
    #pragma unroll
    for (int rt = 0; rt < 4; ++rt) {
      f4_t z = {0.f, 0.f, 0.f, 0.f};
      z = __builtin_amdgcn_mfma_f32_16x16x32_bf16(w0, a1[rt][0], z, 0, 0, 0);
      z = __builtin_amdgcn_mfma_f32_16x16x32_bf16(w1, a1[rt][1], z, 0, 0, 0);
      g[rt] = z;
    }
    int cbase = i * 16 + quad * 4;
    f4_t b4  = *(const f4_t*)&b1s[cbase];
    f4_t wc0 = *(const f4_t*)&wcs[cbase];
    f4_t wc1 = *(const f4_t*)&wcs[256 + cbase];
    #pragma unroll
    for (int rt = 0; rt < 4; ++rt) {
      #pragma unroll
      for (int r = 0; r < 4; ++r) {
        float v = g[rt][r] + b4[r];
        v = v > 0.f ? v : __expf(v) - 1.f;
        p0[rt] = fmaf(v, wc0[r], p0[rt]);
        p1[rt] = fmaf(v, wc1[r], p1[rt]);
      }
    }
  }

  #pragma unroll
  for (int off = 16; off < 64; off <<= 1) {
    #pragma unroll
    for (int rt = 0; rt < 4; ++rt) {
      p0[rt] += __shfl_xor(p0[rt], off, 64);
      p1[rt] += __shfl_xor(p1[rt], off, 64);
    }
  }
  if (quad == 0) {
    float c0 = pc[0], c1 = pc[1];
    #pragma unroll
    for (int rt = 0; rt < 4; ++rt) {
      int row = row_base + rt * 16 + l15;
      if (row < Mtot)
        *(float2*)&pbufN[2 * row] = make_float2(p0[rt] + c0, p1[rt] + c1);
    }
  }
}

// ======================= Heads =======================
__global__ void head_kernel(const float* __restrict__ node_repr, const float* __restrict__ ph,
                            const int* __restrict__ rowptr, const int* __restrict__ csr_eid,
                            const float* __restrict__ pbuf, const float* __restrict__ wu,
                            const float* __restrict__ bu, const float* __restrict__ w2,
                            const float* __restrict__ b2, float* __restrict__ out, int n) {
  __shared__ float swu[128];
  __shared__ float sw2[256];
  int tid = threadIdx.x;
  if (tid < 128) swu[tid] = wu[tid];
  sw2[tid] = w2[tid];
  __syncthreads();
  int i = blockIdx.x * blockDim.x + tid;
  if (i >= n) return;
  float m0 = 0.f, m1 = 0.f;
  int r0 = rowptr[i], r1 = rowptr[i + 1];
  int jj = r0;
  for (; jj + 4 <= r1; jj += 4) {
    int e0 = csr_eid[jj + 0], e1 = csr_eid[jj + 1];
    int e2 = csr_eid[jj + 2], e3 = csr_eid[jj + 3];
    float2 q0 = *(const float2*)&pbuf[2 * e0];
    float2 q1 = *(const float2*)&pbuf[2 * e1];
    float2 q2 = *(const float2*)&pbuf[2 * e2];
    float2 q3 = *(const float2*)&pbuf[2 * e3];
    m0 += (q0.x + q1.x) + (q2.x + q3.x);
    m1 += (q0.y + q1.y) + (q2.y + q3.y);
  }
  for (; jj < r1; ++jj) {
    int e = csr_eid[jj];
    float2 q = *(const float2*)&pbuf[2 * e];
    m0 += q.x; m1 += q.y;
  }
  const float* nr = node_repr + (size_t)i * 64;
  float u0 = bu[0], u1 = bu[1];
  #pragma unroll
  for (int k = 0; k < 64; ++k) {
    float v = nr[k];
    u0 = fmaf(v, swu[2 * k + 0], u0);
    u1 = fmaf(v, swu[2 * k + 1], u1);
  }
  float v0 = u0 + m0;
  float v1 = u1 + m1;
  float mx = fmaxf(v0, v1);
  float lse = mx + logf(__expf(v0 - mx) + __expf(v1 - mx));
  out[2 * i + 0] = v0 - lse;
  out[2 * i + 1] = v1 - lse;
  const float* p = ph + (size_t)i * 128;
  float p0 = b2[0], p1 = b2[1];
  #pragma unroll
  for (int k = 0; k < 128; ++k) {
    float v = p[k];
    p0 = fmaf(v, sw2[2 * k + 0], p0);
    p1 = fmaf(v, sw2[2 * k + 1], p1);
  }
  out[2 * n + 2 * i + 0] = p0;
  out[2 * n + 2 * i + 1] = p1;
}

// ======================= launch =======================
extern "C" void kernel_launch(void* const* d_in, const int* in_sizes, int n_in,
                              void* d_out, int out_size, void* d_ws, size_t ws_size,
                              hipStream_t stream) {
  const int N = N_NODES, E = N_EDGES;
  const float* x         = (const float*)d_in[0];
  const float* edge_type = (const float*)d_in[1];
  const int*   ei        = (const int*)d_in[2];
  const float* n1_wl  = (const float*)d_in[3];
  const float* n1_wr  = (const float*)d_in[4];
  const float* n1_att = (const float*)d_in[5];
  const float* n1_b   = (const float*)d_in[6];
  const float* n2_wl  = (const float*)d_in[7];
  const float* n2_wr  = (const float*)d_in[8];
  const float* n2_att = (const float*)d_in[9];
  const float* n2_b   = (const float*)d_in[10];
  const float* e1_wl  = (const float*)d_in[11];
  const float* e1_wr  = (const float*)d_in[12];
  const float* e1_att = (const float*)d_in[13];
  const float* e1_b   = (const float*)d_in[14];
  const float* e2_wl  = (const float*)d_in[15];
  const float* e2_wr  = (const float*)d_in[16];
  const float* e2_att = (const float*)d_in[17];
  const float* e2_b   = (const float*)d_in[18];
  const float* crf_wu = (const float*)d_in[19];
  const float* crf_bu = (const float*)d_in[20];
  const float* crf_wp = (const float*)d_in[21];
  const float* px_w1  = (const float*)d_in[22];
  const float* px_b1  = (const float*)d_in[23];
  const float* px_w2  = (const float*)d_in[24];
  const float* px_b2  = (const float*)d_in[25];
  float* out = (float*)d_out;
  const int* src = ei;
  const int* dst = ei + E;
  (void)in_sizes; (void)n_in; (void)out_size; (void)ws_size;

  // ---- workspace layout (byte-identical footprint to the verified 452 µs kernel) ----
  char* ws = (char*)d_ws;
  size_t off = 0;
  auto alloc = [&](size_t bytes) -> void* {
    void* p = ws + off;
    off += (bytes + 255) & ~(size_t)255;
    return p;
  };
  half_t* xl_n  = (half_t*)alloc((size_t)N * 256 * 2);
  half_t* xr_n  = (half_t*)alloc((size_t)N * 256 * 2);
  half_t* xl_e  = (half_t*)alloc((size_t)N * 256 * 2);
  half_t* xr_e  = (half_t*)alloc((size_t)N * 256 * 2);
  // h_n / g_e stored as fp16 (allocations keep fp32 sizes -> layout unchanged)
  half_t* h_n  = (half_t*)alloc((size_t)N * 256 * 4);
  half_t* g_e  = (half_t*)alloc((size_t)N * 256 * 4);
  half_t* xl2_n = (half_t*)alloc((size_t)N * 64 * 2);
  half_t* xr2_n = (half_t*)alloc((size_t)N * 64 * 2);
  half_t* xl2_e = (half_t*)alloc((size_t)N * 64 * 2);
  half_t* xr2_e = (half_t*)alloc((size_t)N * 64 * 2);
  float* B3    = (float*)alloc((size_t)N * 64 * 4);
  float* pbuf  = (float*)alloc((size_t)E * 2 * 4);
  float* ph    = (float*)(void*)xl_n;   // reuse 10.24 MB
  int* deg     = (int*)alloc((size_t)N * 4);
  int* rowptr  = (int*)alloc((size_t)(N + 1) * 4);
  int* cursor  = (int*)alloc((size_t)N * 4);
  int* csr_src = (int*)alloc((size_t)E * 4);
  int* csr_eid = (int*)alloc((size_t)E * 4);
  short* t_n1l = (short*)alloc((size_t)16384 * 2);
  short* t_n1r = (short*)alloc((size_t)16384 * 2);
  short* t_e1l = (short*)alloc((size_t)16384 * 2);
  short* t_e1r = (short*)alloc((size_t)16384 * 2);
  short* t_n2l = (short*)alloc((size_t)16384 * 2);
  short* t_n2r = (short*)alloc((size_t)16384 * 2);
  short* t_e2l = (short*)alloc((size_t)16384 * 2);
  short* t_e2r = (short*)alloc((size_t)16384 * 2);
  float* WcT   = (float*)alloc((size_t)2 * 256 * 4);
  float* pcv   = (float*)alloc((size_t)2 * 4);
  // layer-1 linear-logit buffers aliased into pbuf (lifetime-disjoint, see r2 notes)
  float* l1ln = pbuf;
  float* l1rn = pbuf + 80000;
  float* l1le = pbuf + 160000;
  float* l1re = pbuf + 240000;
  // layer-2 linear-logit buffers aliased into xr_n (dead after gat_agg_l1)
  float* l2base = (float*)(void*)xr_n;
  float* l2ln = l2base;
  float* l2rn = l2base + 20000;
  float* l2le = l2base + 40000;
  float* l2re = l2base + 60000;
  // degree-sort scratch: hist/hcur (4 KB) alias head of B3 (first written by l2_agg,
  // long after the sort); order aliases cursor (dead after fill_csr).
  int* hist  = (int*)(void*)B3;
  int* hcur  = hist + 512;
  int* order = cursor;

  const int EB = (E + 255) / 256;
  const int NB = (N + 127) / 128;
  const int PB = (N + 63) / 64;
  const int NB256 = (N + 255) / 256;
  const int Mhigh = E - N;
  const int CFB = (Mhigh + 255) / 256;   // 256-row 4-wave blocks
  const int GRP = N / 4;

  hipMemsetAsync(deg, 0, (size_t)N * 4, stream);
  hipMemsetAsync(hist, 0, 512 * 4, stream);
  count_deg_kernel<<<EB, 256, 0, stream>>>(dst, deg, E);
  scan_kernel<<<1, 1024, 0, stream>>>(deg, rowptr, cursor, N);
  fill_csr_kernel<<<EB, 256, 0, stream>>>(src, dst, cursor, csr_src, csr_eid, E);
  // degree-descending node order for balanced aggregation blocks (LDS-hierarchical)
  deg_hist_kernel<<<NB256, 256, 0, stream>>>(deg, hist, N);
  hist_scan_kernel<<<1, 512, 0, stream>>>(hist, hcur);
  order_scatter_kernel<<<NB256, 256, 0, stream>>>(deg, hcur, order, N);
  prep_all_kernel<<<515, 256, 0, stream>>>(n1_wl, n1_wr, e1_wl, e1_wr,
                                           n2_wl, n2_wr, e2_wl, e2_wr,
                                           e2_b, crf_wp,
                                           t_n1l, t_n1r, t_e1l, t_e1r,
                                           t_n2l, t_n2r, t_e2l, t_e2r, WcT, pcv);

  // ---- layer 1 ----
  mfma_proj2_kernel<64, float><<<dim3(PB, 8, 2), 128, 0, stream>>>(
      x, t_n1l, t_n1r, xl_n, xr_n,
      edge_type, t_e1l, t_e1r, xl_e, xr_e,
      n1_att, e1_att, l1ln, l1rn, l1le, l1re, N, 4);
  gat_agg_l1<<<2 * GRP, 256, 0, stream>>>(
      xl_n, xr_n, n1_att, n1_b, h_n,
      xl_e, xr_e, e1_att, e1_b, g_e,
      l1ln, l1rn, l1le, l1re, rowptr, csr_src, order);

  // ---- layer 2 ----
  mfma_proj2_kernel<256, half_t><<<dim3(PB, 2, 2), 128, 0, stream>>>(
      h_n, t_n2l, t_n2r, xl2_n, xr2_n,
      g_e, t_e2l, t_e2r, xl2_e, xr2_e,
      n2_att, e2_att, l2ln, l2rn, l2le, l2re, N, 1);
  gat_agg_l2<<<2 * GRP, 256, 0, stream>>>(
      xl2_n, xr2_n, n2_att, n2_b, B3,
      xl2_e, xr2_e, e2_att, e2_b,
      l2ln, l2rn, l2le, l2re, rowptr, csr_src, crf_wp, pbuf, order);

  // ---- CRF p for self-loop-only edge rows ----
  chunk_fold_kernel<<<CFB, 256, 0, stream>>>(edge_type + (size_t)N * 64, t_e1l,
                                             e1_b, WcT, pcv, pbuf + 2 * (size_t)N, Mhigh);

  // ---- heads ----
  gemm64_kernel<64, 3><<<dim3(NB, 2), 256, 0, stream>>>(B3, px_w1, 128, px_b1, ph, 128, N);
  head_kernel<<<(N + 255) / 256, 256, 0, stream>>>(B3, ph, rowptr, csr_eid, pbuf,
                                                   crf_wu, crf_bu, px_w2, px_b2, out, N);
}

// Round 12
// 392.339 us; speedup vs baseline: 1.3129x; 1.0391x over previous
//
#include <hip/hip_runtime.h>
#include <cstddef>
#include <cstdint>

#define N_NODES 20000
#define N_EDGES 320000

typedef __attribute__((ext_vector_type(8))) short bf8_t;   // 8 x bf16 (MFMA frag)
typedef __attribute__((ext_vector_type(4))) float f4_t;    // MFMA acc / float4
typedef __attribute__((ext_vector_type(2))) float f2_t;
typedef unsigned short bfu;
typedef _Float16 half_t;
typedef __attribute__((ext_vector_type(2))) _Float16 h2_t;
typedef __attribute__((ext_vector_type(4))) _Float16 h4_t;
typedef __attribute__((ext_vector_type(8))) _Float16 h8_t;

__device__ __forceinline__ short f2bf(float f) {
  unsigned u = __float_as_uint(f);
  u += 0x7fff + ((u >> 16) & 1);   // round-to-nearest-even
  return (short)(u >> 16);
}
// |t| on packed f16 (clear sign bits)
__device__ __forceinline__ h2_t abs_h2(h2_t t) {
  unsigned u = __builtin_bit_cast(unsigned, t) & 0x7fff7fffu;
  return __builtin_bit_cast(h2_t, u);
}
__device__ __forceinline__ float dot2h(h2_t a, h2_t b, float c) {
#if __has_builtin(__builtin_amdgcn_fdot2)
  return __builtin_amdgcn_fdot2(a, b, c, false);
#else
  return c + (float)a.x * (float)b.x + (float)a.y * (float)b.y;
#endif
}

// ======================= CSR build =======================
__global__ void count_deg_kernel(const int* __restrict__ dst, int* __restrict__ deg, int e_cnt) {
  int e = blockIdx.x * blockDim.x + threadIdx.x;
  if (e < e_cnt) atomicAdd(&deg[dst[e]], 1);
}

__global__ __launch_bounds__(1024) void scan_kernel(
    const int* __restrict__ deg, int* __restrict__ rowptr,
    int* __restrict__ cursor, int n) {
  __shared__ int sdata[1024];
  constexpr int CH = (N_NODES + 1023) / 1024;   // compile-time -> loc[] stays in regs
  int tid = threadIdx.x;
  int base = tid * CH;
  int loc[CH];
  int s = 0;
  #pragma unroll
  for (int j = 0; j < CH; ++j) {
    int idx = base + j;
    int v = (idx < n) ? deg[idx] : 0;
    loc[j] = s;
    s += v;
  }
  sdata[tid] = s;
  __syncthreads();
  for (int off = 1; off < 1024; off <<= 1) {
    int t = (tid >= off) ? sdata[tid - off] : 0;
    __syncthreads();
    sdata[tid] += t;
    __syncthreads();
  }
  int excl = sdata[tid] - s;
  #pragma unroll
  for (int j = 0; j < CH; ++j) {
    int idx = base + j;
    if (idx < n) { int val = excl + loc[j]; rowptr[idx] = val; cursor[idx] = val; }
  }
  if (tid == 0) rowptr[n] = sdata[1023];
}

__global__ void fill_csr_kernel(const int* __restrict__ src, const int* __restrict__ dst,
                                int* __restrict__ cursor, int* __restrict__ csr_src,
                                int* __restrict__ csr_eid, int e_cnt) {
  int e = blockIdx.x * blockDim.x + threadIdx.x;
  if (e < e_cnt) {
    int pos = atomicAdd(&cursor[dst[e]], 1);
    csr_src[pos] = src[e];
    csr_eid[pos] = e;
  }
}

// ======================= weight prep =======================
__global__ void prep_all_kernel(
    const float* __restrict__ n1l, const float* __restrict__ n1r,
    const float* __restrict__ e1l, const float* __restrict__ e1r,
    const float* __restrict__ n2l, const float* __restrict__ n2r,
    const float* __restrict__ e2l, const float* __restrict__ e2r,
    const float* __restrict__ b2, const float* __restrict__ wp,
    short* __restrict__ t_n1l, short* __restrict__ t_n1r,
    short* __restrict__ t_e1l, short* __restrict__ t_e1r,
    short* __restrict__ t_n2l, short* __restrict__ t_n2r,
    short* __restrict__ t_e2l, short* __restrict__ t_e2r,
    float* __restrict__ wct, float* __restrict__ pc)
{
  int i = blockIdx.x * blockDim.x + threadIdx.x;
  int seg = i >> 14;
  int j = i & 16383;
  if (seg < 4) {
    const float* srcs[4] = {n1l, n1r, e1l, e1r};
    short* dsts[4] = {t_n1l, t_n1r, t_e1l, t_e1r};
    int n = j >> 6, k = j & 63;
    dsts[seg][n * 64 + k] = f2bf(srcs[seg][k * 256 + n]);
  } else if (seg < 8) {
    const float* srcs[4] = {n2l, n2r, e2l, e2r};
    short* dsts[4] = {t_n2l, t_n2r, t_e2l, t_e2r};
    int n = j >> 8, k = j & 255;
    dsts[seg - 4][n * 256 + k] = f2bf(srcs[seg - 4][k * 64 + n]);
  } else if (seg == 8) {
    if (j < 512) {
      int jj = j & 1;
      int k  = j >> 1;
      float s = 0.f;
      for (int c = 0; c < 64; ++c) s = fmaf(e2l[k * 64 + c], wp[c * 2 + jj], s);
      wct[jj * 256 + k] = s;
    } else if (j < 514) {
      int jj = j - 512;
      float s = 0.f;
      for (int c = 0; c < 64; ++c) s = fmaf(b2[c], wp[c * 2 + jj], s);
      pc[jj] = s;
    }
  }
}

// ======================= MFMA projection kernel (dual-chain, fp16 outputs) ==========
template<int K, typename SrcT>
__global__ __launch_bounds__(128) void mfma_proj2_kernel(
    const SrcT* __restrict__ A0,
    const short* __restrict__ Wtl0, const short* __restrict__ Wtr0,
    half_t* __restrict__ xl0, half_t* __restrict__ xr0,
    const SrcT* __restrict__ A1,
    const short* __restrict__ Wtl1, const short* __restrict__ Wtr1,
    half_t* __restrict__ xl1, half_t* __restrict__ xr1,
    const float* __restrict__ att0, const float* __restrict__ att1,
    float* __restrict__ ll0, float* __restrict__ lr0,
    float* __restrict__ ll1, float* __restrict__ lr1,
    int M, int nslices)
{
  constexpr int KC = K / 32;
  int tid = threadIdx.x;
  int w = tid >> 6, lane = tid & 63, quad = lane >> 4, l15 = lane & 15;
  int row_base = (int)blockIdx.x * 64 + w * 32;
  int y = (int)blockIdx.y;
  int z = (int)blockIdx.z;
  const SrcT* A = z ? A1 : A0;
  bool is_l = y < nslices;
  const short* Wt = z ? (is_l ? Wtl1 : Wtr1) : (is_l ? Wtl0 : Wtr0);
  half_t* dst = z ? (is_l ? xl1 : xr1) : (is_l ? xl0 : xr0);
  const float* att = z ? att1 : att0;
  float* lin = z ? (is_l ? ll1 : lr1) : (is_l ? ll0 : lr0);
  int head = is_l ? y : y - nslices;
  int cb = head * 64;
  const float* atp = att + head * 64;
  int STR = nslices * 64;

  bf8_t a[2][KC];
  #pragma unroll
  for (int rt = 0; rt < 2; ++rt) {
    int r = row_base + rt * 16 + l15;
    int rc = r < M ? r : M - 1;
    const SrcT* ap = A + (size_t)rc * K + quad * 8;
    #pragma unroll
    for (int kc = 0; kc < KC; ++kc) {
      bf8_t f;
      if constexpr (sizeof(SrcT) == 4) {
        float4 v0 = *(const float4*)(ap + kc * 32);
        float4 v1 = *(const float4*)(ap + kc * 32 + 4);
        f[0] = f2bf(v0.x); f[1] = f2bf(v0.y); f[2] = f2bf(v0.z); f[3] = f2bf(v0.w);
        f[4] = f2bf(v1.x); f[5] = f2bf(v1.y); f[6] = f2bf(v1.z); f[7] = f2bf(v1.w);
      } else {
        h8_t hv = *(const h8_t*)(ap + kc * 32);
        #pragma unroll
        for (int q = 0; q < 8; ++q) f[q] = f2bf((float)hv[q]);
      }
      a[rt][kc] = f;
    }
  }

  float lacc0 = 0.f, lacc1 = 0.f;
  #pragma unroll
  for (int nt = 0; nt < 4; ++nt) {
    f4_t acc0 = {0.f, 0.f, 0.f, 0.f};
    f4_t acc1 = {0.f, 0.f, 0.f, 0.f};
    const short* wb = Wt + (size_t)(cb + nt * 16 + l15) * K + quad * 8;
    #pragma unroll
    for (int kc = 0; kc < KC; ++kc) {
      bf8_t wf = *(const bf8_t*)(wb + kc * 32);
      acc0 = __builtin_amdgcn_mfma_f32_16x16x32_bf16(wf, a[0][kc], acc0, 0, 0, 0);
      acc1 = __builtin_amdgcn_mfma_f32_16x16x32_bf16(wf, a[1][kc], acc1, 0, 0, 0);
    }
    // att-dot for the linear logit part (cols nt*16 + quad*4 + j of this head)
    f4_t av = *(const f4_t*)(atp + nt * 16 + quad * 4);
    lacc0 += acc0[0] * av[0] + acc0[1] * av[1] + acc0[2] * av[2] + acc0[3] * av[3];
    lacc1 += acc1[0] * av[0] + acc1[1] * av[1] + acc1[2] * av[2] + acc1[3] * av[3];
    #pragma unroll
    for (int rt = 0; rt < 2; ++rt) {
      f4_t acc = rt == 0 ? acc0 : acc1;
      int row = row_base + rt * 16 + l15;
      if (row >= M) continue;
      int col = cb + nt * 16 + quad * 4;
      h4_t pk;
      pk[0] = (_Float16)acc[0]; pk[1] = (_Float16)acc[1];
      pk[2] = (_Float16)acc[2]; pk[3] = (_Float16)acc[3];
      *(h4_t*)&dst[(size_t)row * STR + col] = pk;
    }
  }
  // reduce lacc across the 4 quads (each quad covered a disjoint col subset)
  lacc0 += __shfl_xor(lacc0, 16, 64); lacc0 += __shfl_xor(lacc0, 32, 64);
  lacc1 += __shfl_xor(lacc1, 16, 64); lacc1 += __shfl_xor(lacc1, 32, 64);
  if (quad == 0) {
    int r0 = row_base + l15;
    int r1 = row_base + 16 + l15;
    if (r0 < M) lin[(size_t)r0 * nslices + head] = 0.6f * lacc0;
    if (r1 < M) lin[(size_t)r1 * nslices + head] = 0.6f * lacc1;
  }
}

// ======================= fp32 GEMM (proxy head only) =======================
template<int KIN>
__device__ __forceinline__ void gemm_body(
    const float* __restrict__ A, const float* __restrict__ W, int wld, int cb,
    int block_m, int M, float (&acc)[8][4],
    float (*As)[128 + 4], float (*Ws)[64 + 4])
{
  int tid = threadIdx.x;
  int tx = tid & 15;
  int ty = tid >> 4;
  #pragma unroll
  for (int i = 0; i < 8; ++i)
    #pragma unroll
    for (int j = 0; j < 4; ++j) acc[i][j] = 0.f;

  for (int k0 = 0; k0 < KIN; k0 += 16) {
    #pragma unroll
    for (int rep = 0; rep < 2; ++rep) {
      int ar = (tid >> 2) + rep * 64;
      int ak = (tid & 3) * 4;
      int gr = block_m + ar;
      float4 v = make_float4(0.f, 0.f, 0.f, 0.f);
      if (gr < M) v = *(const float4*)&A[(size_t)gr * KIN + k0 + ak];
      As[ak + 0][ar] = v.x; As[ak + 1][ar] = v.y;
      As[ak + 2][ar] = v.z; As[ak + 3][ar] = v.w;
    }
    {
      int wr = tid >> 4;
      int wc = (tid & 15) * 4;
      float4 v = *(const float4*)&W[(size_t)(k0 + wr) * wld + cb + wc];
      Ws[wr][wc + 0] = v.x; Ws[wr][wc + 1] = v.y;
      Ws[wr][wc + 2] = v.z; Ws[wr][wc + 3] = v.w;
    }
    __syncthreads();
    #pragma unroll
    for (int k = 0; k < 16; ++k) {
      float a[8], w[4];
      #pragma unroll
      for (int i = 0; i < 8; ++i) a[i] = As[k][ty * 8 + i];
      #pragma unroll
      for (int j = 0; j < 4; ++j) w[j] = Ws[k][tx * 4 + j];
      #pragma unroll
      for (int i = 0; i < 8; ++i)
        #pragma unroll
        for (int j = 0; j < 4; ++j) acc[i][j] = fmaf(a[i], w[j], acc[i][j]);
    }
    __syncthreads();
  }
}

template<int KIN, int MODE>
__global__ __launch_bounds__(256) void gemm64_kernel(
    const float* __restrict__ A, const float* __restrict__ W, int wld,
    const float* __restrict__ bias, float* __restrict__ out, int old, int M)
{
  __shared__ float As[16][128 + 4];
  __shared__ float Ws[16][64 + 4];
  float acc[8][4];
  int block_m = (int)blockIdx.x * 128;
  int cb = (int)blockIdx.y * 64;
  gemm_body<KIN>(A, W, wld, cb, block_m, M, acc, As, Ws);

  int tid = threadIdx.x;
  int tx = tid & 15, ty = tid >> 4;
  int gc = cb + tx * 4;
  #pragma unroll
  for (int i = 0; i < 8; ++i) {
    int gr = block_m + ty * 8 + i;
    if (gr >= M) continue;
    size_t idx = (size_t)gr * old + gc;
    float t0 = acc[i][0], t1 = acc[i][1], t2 = acc[i][2], t3 = acc[i][3];
    if (MODE == 3) {
      t0 = fmaxf(t0 + bias[gc + 0], 0.f);
      t1 = fmaxf(t1 + bias[gc + 1], 0.f);
      t2 = fmaxf(t2 + bias[gc + 2], 0.f);
      t3 = fmaxf(t3 + bias[gc + 3], 0.f);
    }
    *(float4*)&out[idx] = make_float4(t0, t1, t2, t3);
  }
}

// ======================= GATv2 aggregation, layer 1 (4 heads fused per wave) ==========
// Lane layout: egrp = lane>>5 (2 edge slots), head = (lane>>3)&3, cch = lane&7.
// Column offset = (lane&31)*8 covers all 256 channels per half-wave (coalesced 512B).
// Logit uses leaky decomposition: logit = linL[s,h] + linR[d,h] + dot(|xl+xr|, 0.4*att).
// Output h (post-ELU) stored as fp16.
__global__ __launch_bounds__(256) void gat_agg_l1(
    const half_t* __restrict__ xl0, const half_t* __restrict__ xr0,
    const float* __restrict__ att0, const float* __restrict__ bias0,
    half_t* __restrict__ out0,
    const half_t* __restrict__ xl1, const half_t* __restrict__ xr1,
    const float* __restrict__ att1, const float* __restrict__ bias1,
    half_t* __restrict__ out1,
    const float* __restrict__ ll0, const float* __restrict__ lr0,
    const float* __restrict__ ll1, const float* __restrict__ lr1,
    const int* __restrict__ rowptr, const int* __restrict__ csr_src)
{
  constexpr int GRP = N_NODES / 4;
  int tid = threadIdx.x;
  int w = tid >> 6, lane = tid & 63;
  int egrp = lane >> 5;
  int head = (lane >> 3) & 3;
  int coff = (lane & 31) * 8;
  int bid = (int)blockIdx.x;
  int chain = bid >= GRP ? 1 : 0;
  int d = (bid - chain * GRP) * 4 + w;

  const half_t* xl = chain ? xl1 : xl0;
  const half_t* xr = chain ? xr1 : xr0;
  const float* att = chain ? att1 : att0;
  const float* bias = chain ? bias1 : bias0;
  const float* linl = chain ? ll1 : ll0;
  const float* linr = chain ? lr1 : lr0;
  half_t* out = chain ? out1 : out0;

  int row0 = rowptr[d];
  int deg = rowptr[d + 1] - row0;

  h2_t xr2[4], attA[4];
  {
    h8_t xv = *(const h8_t*)&xr[(unsigned)(d * 256 + coff)];
    xr2[0] = h2_t{xv[0], xv[1]}; xr2[1] = h2_t{xv[2], xv[3]};
    xr2[2] = h2_t{xv[4], xv[5]}; xr2[3] = h2_t{xv[6], xv[7]};
    const float* atp = att + coff;
    float4 b0 = *(const float4*)(atp);
    float4 b1 = *(const float4*)(atp + 4);
    attA[0] = h2_t{(_Float16)(0.4f * b0.x), (_Float16)(0.4f * b0.y)};
    attA[1] = h2_t{(_Float16)(0.4f * b0.z), (_Float16)(0.4f * b0.w)};
    attA[2] = h2_t{(_Float16)(0.4f * b1.x), (_Float16)(0.4f * b1.y)};
    attA[3] = h2_t{(_Float16)(0.4f * b1.z), (_Float16)(0.4f * b1.w)};
  }
  float linr_d = linr[(unsigned)(d * 4 + head)];

  auto ld_idx = [&](int k) -> int {
    int idx = k * 2 + egrp;
    int cl = idx < deg ? idx : (deg > 0 ? deg - 1 : 0);
    int pos = deg > 0 ? row0 + cl : 0;
    int sv = csr_src[pos];
    return idx < deg ? sv : d;
  };

  float zloc, a8[8];
  {
    // self loop (counted once via egrp==0 mask)
    h8_t xu = *(const h8_t*)&xl[(unsigned)(d * 256 + coff)];
    float part = 0.f;
    #pragma unroll
    for (int j = 0; j < 4; ++j) {
      h2_t t = h2_t{xu[2 * j], xu[2 * j + 1]} + xr2[j];
      part = dot2h(abs_h2(t), attA[j], part);
    }
    part += __shfl_xor(part, 1, 64);
    part += __shfl_xor(part, 2, 64);
    part += __shfl_xor(part, 4, 64);
    part += linl[(unsigned)(d * 4 + head)] + linr_d;
    float wgt = __expf(part);
    float ws = (egrp == 0) ? wgt : 0.f;
    zloc = ws;
    #pragma unroll
    for (int i = 0; i < 8; ++i) a8[i] = (float)xu[i] * ws;
  }

  int C = (deg + 1) >> 1;
  int s_cur = ld_idx(0);
  h8_t xu_cur = *(const h8_t*)&xl[(unsigned)(s_cur * 256 + coff)];
  float lin_cur = linl[(unsigned)(s_cur * 4 + head)];
  int s_nxt = ld_idx(1);
  for (int k = 0; k < C; ++k) {
    h8_t xu_nxt = *(const h8_t*)&xl[(unsigned)(s_nxt * 256 + coff)];
    float lin_nxt = linl[(unsigned)(s_nxt * 4 + head)];
    int s_n2 = ld_idx(k + 2);
    bool valid = (k * 2 + egrp) < deg;
    float part = 0.f;
    #pragma unroll
    for (int j = 0; j < 4; ++j) {
      h2_t t = h2_t{xu_cur[2 * j], xu_cur[2 * j + 1]} + xr2[j];
      part = dot2h(abs_h2(t), attA[j], part);
    }
    part += __shfl_xor(part, 1, 64);
    part += __shfl_xor(part, 2, 64);
    part += __shfl_xor(part, 4, 64);
    part += lin_cur + linr_d;
    float wgt = valid ? __expf(part) : 0.f;
    zloc += wgt;
    #pragma unroll
    for (int i = 0; i < 8; ++i) a8[i] = fmaf((float)xu_cur[i], wgt, a8[i]);
    xu_cur = xu_nxt; lin_cur = lin_nxt; s_nxt = s_n2;
  }

  // combine the two edge-slot halves
  zloc += __shfl_xor(zloc, 32, 64);
  #pragma unroll
  for (int i = 0; i < 8; ++i) a8[i] += __shfl_xor(a8[i], 32, 64);

  if (egrp == 0) {
    float invz = 1.f / zloc;
    const float* bp = bias + coff;
    float4 c0 = *(const float4*)(bp);
    float4 c1 = *(const float4*)(bp + 4);
    float o[8];
    o[0] = a8[0] * invz + c0.x; o[1] = a8[1] * invz + c0.y;
    o[2] = a8[2] * invz + c0.z; o[3] = a8[3] * invz + c0.w;
    o[4] = a8[4] * invz + c1.x; o[5] = a8[5] * invz + c1.y;
    o[6] = a8[6] * invz + c1.z; o[7] = a8[7] * invz + c1.w;
    #pragma unroll
    for (int i = 0; i < 8; ++i) o[i] = o[i] > 0.f ? o[i] : __expf(o[i]) - 1.f;  // ELU
    h8_t pk;
    #pragma unroll
    for (int i = 0; i < 8; ++i) pk[i] = (_Float16)o[i];
    *(h8_t*)&out[(size_t)d * 256 + coff] = pk;   // single 16B fp16 store
  }
}

// ======================= GATv2 aggregation, layer 2 (1 head, abs-trick, fused p) ======
__global__ __launch_bounds__(256) void gat_agg_l2(
    const half_t* __restrict__ xl0, const half_t* __restrict__ xr0,
    const float* __restrict__ att0, const float* __restrict__ bias0,
    float* __restrict__ out0,
    const half_t* __restrict__ xl1, const half_t* __restrict__ xr1,
    const float* __restrict__ att1, const float* __restrict__ bias1,
    const float* __restrict__ ll0, const float* __restrict__ lr0,
    const float* __restrict__ ll1, const float* __restrict__ lr1,
    const int* __restrict__ rowptr, const int* __restrict__ csr_src,
    const float* __restrict__ wp, float* __restrict__ pbuf)
{
  constexpr int GRP = N_NODES / 4;
  int tid = threadIdx.x;
  int w = tid >> 6;
  int lane = tid & 63;
  int egrp = lane >> 3;
  int cch  = lane & 7;
  int bid = (int)blockIdx.x;
  int chain = bid >= GRP ? 1 : 0;
  int d = (bid - chain * GRP) * 4 + w;

  const half_t* xl = chain ? xl1 : xl0;
  const half_t* xr = chain ? xr1 : xr0;
  const float* att = chain ? att1 : att0;
  const float* bias = chain ? bias1 : bias0;
  const float* linl = chain ? ll1 : ll0;
  const float* linr = chain ? lr1 : lr0;

  int row0 = rowptr[d];
  int deg = rowptr[d + 1] - row0;
  int cbase = cch * 8;

  h2_t xr2[4], attA[4];
  {
    h8_t xv = *(const h8_t*)&xr[(unsigned)(d * 64 + cbase)];
    xr2[0] = h2_t{xv[0], xv[1]}; xr2[1] = h2_t{xv[2], xv[3]};
    xr2[2] = h2_t{xv[4], xv[5]}; xr2[3] = h2_t{xv[6], xv[7]};
    const float* atp = att + cbase;
    float4 b0 = *(const float4*)(atp);
    float4 b1 = *(const float4*)(atp + 4);
    attA[0] = h2_t{(_Float16)(0.4f * b0.x), (_Float16)(0.4f * b0.y)};
    attA[1] = h2_t{(_Float16)(0.4f * b0.z), (_Float16)(0.4f * b0.w)};
    attA[2] = h2_t{(_Float16)(0.4f * b1.x), (_Float16)(0.4f * b1.y)};
    attA[3] = h2_t{(_Float16)(0.4f * b1.z), (_Float16)(0.4f * b1.w)};
  }
  float linr_d = linr[d];

  auto ld_idx = [&](int k) -> int {
    int idx = k * 8 + egrp;
    int cl = idx < deg ? idx : (deg > 0 ? deg - 1 : 0);
    int pos = deg > 0 ? row0 + cl : 0;
    int sv = csr_src[pos];
    return idx < deg ? sv : d;
  };

  float zloc, a8[8];
  {
    h8_t xu = *(const h8_t*)&xl[(unsigned)(d * 64 + cbase)];
    float part = 0.f;
    #pragma unroll
    for (int j = 0; j < 4; ++j) {
      h2_t t = h2_t{xu[2 * j], xu[2 * j + 1]} + xr2[j];
      part = dot2h(abs_h2(t), attA[j], part);
    }
    part += __shfl_xor(part, 1, 64);
    part += __shfl_xor(part, 2, 64);
    part += __shfl_xor(part, 4, 64);
    part += linl[d] + linr_d;
    float wgt = __expf(part);
    float ws = (egrp == 0) ? wgt : 0.f;
    zloc = ws;
    #pragma unroll
    for (int i = 0; i < 8; ++i) a8[i] = (float)xu[i] * ws;
  }

  int C = (deg + 7) >> 3;
  int s_cur = ld_idx(0);
  h8_t xu_cur = *(const h8_t*)&xl[(unsigned)(s_cur * 64 + cbase)];
  float lin_cur = linl[s_cur];
  int s_nxt = ld_idx(1);
  for (int k = 0; k < C; ++k) {
    h8_t xu_nxt = *(const h8_t*)&xl[(unsigned)(s_nxt * 64 + cbase)];
    float lin_nxt = linl[s_nxt];
    int s_n2 = ld_idx(k + 2);
    bool valid = (k * 8 + egrp) < deg;
    float part = 0.f;
    #pragma unroll
    for (int j = 0; j < 4; ++j) {
      h2_t t = h2_t{xu_cur[2 * j], xu_cur[2 * j + 1]} + xr2[j];
      part = dot2h(abs_h2(t), attA[j], part);
    }
    part += __shfl_xor(part, 1, 64);
    part += __shfl_xor(part, 2, 64);
    part += __shfl_xor(part, 4, 64);
    part += lin_cur + linr_d;
    float wgt = valid ? __expf(part) : 0.f;
    zloc += wgt;
    #pragma unroll
    for (int i = 0; i < 8; ++i) a8[i] = fmaf((float)xu_cur[i], wgt, a8[i]);
    xu_cur = xu_nxt; lin_cur = lin_nxt; s_nxt = s_n2;
  }

  #pragma unroll
  for (int off = 8; off < 64; off <<= 1) {
    zloc += __shfl_xor(zloc, off, 64);
    #pragma unroll
    for (int i = 0; i < 8; ++i) a8[i] += __shfl_xor(a8[i], off, 64);
  }

  float invz = 1.f / zloc;
  float o[8];
  #pragma unroll
  for (int i = 0; i < 8; ++i) o[i] = a8[i] * invz + bias[cbase + i];

  if (chain) {
    // fold directly into CRF pairwise message p = (out) @ wp
    float p0 = 0.f, p1 = 0.f;
    #pragma unroll
    for (int i = 0; i < 8; ++i) {
      float2 wv = *(const float2*)&wp[(cbase + i) * 2];
      p0 = fmaf(o[i], wv.x, p0);
      p1 = fmaf(o[i], wv.y, p1);
    }
    p0 += __shfl_xor(p0, 1, 64); p1 += __shfl_xor(p1, 1, 64);
    p0 += __shfl_xor(p0, 2, 64); p1 += __shfl_xor(p1, 2, 64);
    p0 += __shfl_xor(p0, 4, 64); p1 += __shfl_xor(p1, 4, 64);
    if (lane == 0) *(float2*)&pbuf[2 * d] = make_float2(p0, p1);
  } else if (egrp == 0) {
    float* op = out0 + (size_t)d * 64 + cbase;
    *(float4*)(op)     = make_float4(o[0], o[1], o[2], o[3]);
    *(float4*)(op + 4) = make_float4(o[4], o[5], o[6], o[7]);
  }
}

// ======================= folded chunk kernel v8 (W in LDS, spill-free) ===============
__global__ __launch_bounds__(256) void chunk_fold_kernel(
    const float* __restrict__ A,
    const short* __restrict__ W1t,
    const float* __restrict__ b1,
    const float* __restrict__ WcT,
    const float* __restrict__ pc,
    float* __restrict__ pbufN,
    int Mtot)
{
  __shared__ short Ws[256 * 72];   // 36864 B, stride 72 shorts = bank-balanced for b128
  __shared__ float b1s[256];
  __shared__ float wcs[512];

  int tid = threadIdx.x;
  int w = tid >> 6;
  int lane = tid & 63;
  int quad = lane >> 4;
  int l15 = lane & 15;
  int row_base = (int)blockIdx.x * 256 + w * 64;

  // Phase 1: cooperative staging of W (32 KB) + tables into LDS.
  #pragma unroll
  for (int j = 0; j < 8; ++j) {
    int g = j * 256 + tid;
    int row = g >> 3, c = g & 7;
    *(int4*)&Ws[row * 72 + c * 8] = *(const int4*)&W1t[(size_t)g * 8];
  }
  b1s[tid] = b1[tid];
  wcs[tid] = WcT[tid];
  wcs[256 + tid] = WcT[256 + tid];
  __syncthreads();

  // Phase 2: A load + convert (no liveness across the barrier)
  bf8_t a1[4][2];
  #pragma unroll
  for (int rt = 0; rt < 4; ++rt) {
    int r = row_base + rt * 16 + l15;
    int rc = r < Mtot ? r : Mtot - 1;
    const float* ap = A + (size_t)rc * 64 + quad * 8;
    #pragma unroll
    for (int ks = 0; ks < 2; ++ks) {
      float4 v0 = *(const float4*)(ap + ks * 32);
      float4 v1 = *(const float4*)(ap + ks * 32 + 4);
      bf8_t f;
      f[0] = f2bf(v0.x); f[1] = f2bf(v0.y); f[2] = f2bf(v0.z); f[3] = f2bf(v0.w);
      f[4] = f2bf(v1.x); f[5] = f2bf(v1.y); f[6] = f2bf(v1.z); f[7] = f2bf(v1.w);
      a1[rt][ks] = f;
    }
  }

  float p0[4] = {0.f, 0.f, 0.f, 0.f};
  float p1[4] = {0.f, 0.f, 0.f, 0.f};

  // Phase 3: 16-iteration loop, LDS + registers only.
  #pragma unroll
  for (int i = 0; i < 16; ++i) {
    const short* wl = &Ws[(i * 16 + l15) * 72 + quad * 8];
    bf8_t w0 = *(const bf8_t*)(wl);
    bf8_t w1 = *(const bf8_t*)(wl + 32);

    f4_t g[4];
    #pragma unroll
    for (int rt = 0; rt < 4; ++rt) {
      f4_t z = {0.f, 0.f, 0.f, 0.f};
      z = __builtin_amdgcn_mfma_f32_16x16x32_bf16(w0, a1[rt][0], z, 0, 0, 0);
      z = __builtin_amdgcn_mfma_f32_16x16x32_bf16(w1, a1[rt][1], z, 0, 0, 0);
      g[rt] = z;
    }
    int cbase = i * 16 + quad * 4;
    f4_t b4  = *(const f4_t*)&b1s[cbase];
    f4_t wc0 = *(const f4_t*)&wcs[cbase];
    f4_t wc1 = *(const f4_t*)&wcs[256 + cbase];
    #pragma unroll
    for (int rt = 0; rt < 4; ++rt) {
      #pragma unroll
      for (int r = 0; r < 4; ++r) {
        float v = g[rt][r] + b4[r];
        v = v > 0.f ? v : __expf(v) - 1.f;
        p0[rt] = fmaf(v, wc0[r], p0[rt]);
        p1[rt] = fmaf(v, wc1[r], p1[rt]);
      }
    }
  }

  #pragma unroll
  for (int off = 16; off < 64; off <<= 1) {
    #pragma unroll
    for (int rt = 0; rt < 4; ++rt) {
      p0[rt] += __shfl_xor(p0[rt], off, 64);
      p1[rt] += __shfl_xor(p1[rt], off, 64);
    }
  }
  if (quad == 0) {
    float c0 = pc[0], c1 = pc[1];
    #pragma unroll
    for (int rt = 0; rt < 4; ++rt) {
      int row = row_base + rt * 16 + l15;
      if (row < Mtot)
        *(float2*)&pbufN[2 * row] = make_float2(p0[rt] + c0, p1[rt] + c1);
    }
  }
}

// ======================= Heads (half-wave per node) =======================
// Old version: 79 blocks, per-thread 128-deep serial fma chains -> latency-bound.
// v2: 32 lanes split the edge gather + unary(64ch) + proxy(128ch) dots; 5-level
// width-32 shuffle reduce; 2500 blocks. All loads coalesced (float2/float4).
__global__ __launch_bounds__(256) void head_kernel(
    const float* __restrict__ node_repr, const float* __restrict__ ph,
    const int* __restrict__ rowptr, const int* __restrict__ csr_eid,
    const float* __restrict__ pbuf, const float* __restrict__ wu,
    const float* __restrict__ bu, const float* __restrict__ w2,
    const float* __restrict__ b2, float* __restrict__ out, int n) {
  int tid = threadIdx.x;
  int half = tid >> 5;          // 8 half-waves per block
  int lane32 = tid & 31;
  int i = blockIdx.x * 8 + half;
  if (i >= n) return;

  // pairwise message sum over this node's incoming edges (lanes stride the list)
  float m0 = 0.f, m1 = 0.f;
  int r0 = rowptr[i], r1 = rowptr[i + 1];
  for (int jj = r0 + lane32; jj < r1; jj += 32) {
    int e = csr_eid[jj];
    float2 q = *(const float2*)&pbuf[2 * e];
    m0 += q.x; m1 += q.y;
  }
  // unary: channels 2*lane32, 2*lane32+1 (wu is [64][2] row-major)
  {
    float2 nv = *(const float2*)&node_repr[(size_t)i * 64 + 2 * lane32];
    float4 wv = *(const float4*)&wu[4 * lane32];
    m0 = fmaf(nv.x, wv.x, fmaf(nv.y, wv.z, m0));
    m1 = fmaf(nv.x, wv.y, fmaf(nv.y, wv.w, m1));
  }
  // proxy: channels 4*lane32 .. +3 (w2 is [128][2] row-major)
  float p0, p1;
  {
    float4 pv  = *(const float4*)&ph[(size_t)i * 128 + 4 * lane32];
    float4 w20 = *(const float4*)&w2[8 * lane32];
    float4 w21 = *(const float4*)&w2[8 * lane32 + 4];
    p0 = pv.x * w20.x + pv.y * w20.z + pv.z * w21.x + pv.w * w21.z;
    p1 = pv.x * w20.y + pv.y * w20.w + pv.z * w21.y + pv.w * w21.w;
  }
  // width-32 reduce (xor offsets < 32 stay within the half-wave)
  #pragma unroll
  for (int off = 1; off < 32; off <<= 1) {
    m0 += __shfl_xor(m0, off, 64);
    m1 += __shfl_xor(m1, off, 64);
    p0 += __shfl_xor(p0, off, 64);
    p1 += __shfl_xor(p1, off, 64);
  }
  if (lane32 == 0) {
    float v0 = m0 + bu[0], v1 = m1 + bu[1];
    float mx = fmaxf(v0, v1);
    float lse = mx + logf(__expf(v0 - mx) + __expf(v1 - mx));
    out[2 * i + 0] = v0 - lse;
    out[2 * i + 1] = v1 - lse;
    out[2 * n + 2 * i + 0] = p0 + b2[0];
    out[2 * n + 2 * i + 1] = p1 + b2[1];
  }
}

// ======================= launch =======================
extern "C" void kernel_launch(void* const* d_in, const int* in_sizes, int n_in,
                              void* d_out, int out_size, void* d_ws, size_t ws_size,
                              hipStream_t stream) {
  const int N = N_NODES, E = N_EDGES;
  const float* x         = (const float*)d_in[0];
  const float* edge_type = (const float*)d_in[1];
  const int*   ei        = (const int*)d_in[2];
  const float* n1_wl  = (const float*)d_in[3];
  const float* n1_wr  = (const float*)d_in[4];
  const float* n1_att = (const float*)d_in[5];
  const float* n1_b   = (const float*)d_in[6];
  const float* n2_wl  = (const float*)d_in[7];
  const float* n2_wr  = (const float*)d_in[8];
  const float* n2_att = (const float*)d_in[9];
  const float* n2_b   = (const float*)d_in[10];
  const float* e1_wl  = (const float*)d_in[11];
  const float* e1_wr  = (const float*)d_in[12];
  const float* e1_att = (const float*)d_in[13];
  const float* e1_b   = (const float*)d_in[14];
  const float* e2_wl  = (const float*)d_in[15];
  const float* e2_wr  = (const float*)d_in[16];
  const float* e2_att = (const float*)d_in[17];
  const float* e2_b   = (const float*)d_in[18];
  const float* crf_wu = (const float*)d_in[19];
  const float* crf_bu = (const float*)d_in[20];
  const float* crf_wp = (const float*)d_in[21];
  const float* px_w1  = (const float*)d_in[22];
  const float* px_b1  = (const float*)d_in[23];
  const float* px_w2  = (const float*)d_in[24];
  const float* px_b2  = (const float*)d_in[25];
  float* out = (float*)d_out;
  const int* src = ei;
  const int* dst = ei + E;
  (void)in_sizes; (void)n_in; (void)out_size; (void)ws_size;

  // ---- workspace layout (byte-identical footprint to the verified 452 µs kernel) ----
  char* ws = (char*)d_ws;
  size_t off = 0;
  auto alloc = [&](size_t bytes) -> void* {
    void* p = ws + off;
    off += (bytes + 255) & ~(size_t)255;
    return p;
  };
  half_t* xl_n  = (half_t*)alloc((size_t)N * 256 * 2);
  half_t* xr_n  = (half_t*)alloc((size_t)N * 256 * 2);
  half_t* xl_e  = (half_t*)alloc((size_t)N * 256 * 2);
  half_t* xr_e  = (half_t*)alloc((size_t)N * 256 * 2);
  // h_n / g_e stored as fp16 (allocations keep fp32 sizes -> layout unchanged)
  half_t* h_n  = (half_t*)alloc((size_t)N * 256 * 4);
  half_t* g_e  = (half_t*)alloc((size_t)N * 256 * 4);
  half_t* xl2_n = (half_t*)alloc((size_t)N * 64 * 2);
  half_t* xr2_n = (half_t*)alloc((size_t)N * 64 * 2);
  half_t* xl2_e = (half_t*)alloc((size_t)N * 64 * 2);
  half_t* xr2_e = (half_t*)alloc((size_t)N * 64 * 2);
  float* B3    = (float*)alloc((size_t)N * 64 * 4);
  float* pbuf  = (float*)alloc((size_t)E * 2 * 4);
  float* ph    = (float*)(void*)xl_n;   // reuse 10.24 MB
  int* deg     = (int*)alloc((size_t)N * 4);
  int* rowptr  = (int*)alloc((size_t)(N + 1) * 4);
  int* cursor  = (int*)alloc((size_t)N * 4);
  int* csr_src = (int*)alloc((size_t)E * 4);
  int* csr_eid = (int*)alloc((size_t)E * 4);
  short* t_n1l = (short*)alloc((size_t)16384 * 2);
  short* t_n1r = (short*)alloc((size_t)16384 * 2);
  short* t_e1l = (short*)alloc((size_t)16384 * 2);
  short* t_e1r = (short*)alloc((size_t)16384 * 2);
  short* t_n2l = (short*)alloc((size_t)16384 * 2);
  short* t_n2r = (short*)alloc((size_t)16384 * 2);
  short* t_e2l = (short*)alloc((size_t)16384 * 2);
  short* t_e2r = (short*)alloc((size_t)16384 * 2);
  float* WcT   = (float*)alloc((size_t)2 * 256 * 4);
  float* pcv   = (float*)alloc((size_t)2 * 4);
  // layer-1 linear-logit buffers aliased into pbuf (lifetime-disjoint, see r2 notes)
  float* l1ln = pbuf;
  float* l1rn = pbuf + 80000;
  float* l1le = pbuf + 160000;
  float* l1re = pbuf + 240000;
  // layer-2 linear-logit buffers aliased into xr_n (dead after gat_agg_l1)
  float* l2base = (float*)(void*)xr_n;
  float* l2ln = l2base;
  float* l2rn = l2base + 20000;
  float* l2le = l2base + 40000;
  float* l2re = l2base + 60000;

  const int EB = (E + 255) / 256;
  const int NB = (N + 127) / 128;
  const int PB = (N + 63) / 64;
  const int Mhigh = E - N;
  const int CFB = (Mhigh + 255) / 256;   // 256-row 4-wave blocks
  const int GRP = N / 4;

  hipMemsetAsync(deg, 0, (size_t)N * 4, stream);
  count_deg_kernel<<<EB, 256, 0, stream>>>(dst, deg, E);
  scan_kernel<<<1, 1024, 0, stream>>>(deg, rowptr, cursor, N);
  fill_csr_kernel<<<EB, 256, 0, stream>>>(src, dst, cursor, csr_src, csr_eid, E);
  prep_all_kernel<<<515, 256, 0, stream>>>(n1_wl, n1_wr, e1_wl, e1_wr,
                                           n2_wl, n2_wr, e2_wl, e2_wr,
                                           e2_b, crf_wp,
                                           t_n1l, t_n1r, t_e1l, t_e1r,
                                           t_n2l, t_n2r, t_e2l, t_e2r, WcT, pcv);

  // ---- layer 1 ----
  mfma_proj2_kernel<64, float><<<dim3(PB, 8, 2), 128, 0, stream>>>(
      x, t_n1l, t_n1r, xl_n, xr_n,
      edge_type, t_e1l, t_e1r, xl_e, xr_e,
      n1_att, e1_att, l1ln, l1rn, l1le, l1re, N, 4);
  gat_agg_l1<<<2 * GRP, 256, 0, stream>>>(
      xl_n, xr_n, n1_att, n1_b, h_n,
      xl_e, xr_e, e1_att, e1_b, g_e,
      l1ln, l1rn, l1le, l1re, rowptr, csr_src);

  // ---- layer 2 ----
  mfma_proj2_kernel<256, half_t><<<dim3(PB, 2, 2), 128, 0, stream>>>(
      h_n, t_n2l, t_n2r, xl2_n, xr2_n,
      g_e, t_e2l, t_e2r, xl2_e, xr2_e,
      n2_att, e2_att, l2ln, l2rn, l2le, l2re, N, 1);
  gat_agg_l2<<<2 * GRP, 256, 0, stream>>>(
      xl2_n, xr2_n, n2_att, n2_b, B3,
      xl2_e, xr2_e, e2_att, e2_b,
      l2ln, l2rn, l2le, l2re, rowptr, csr_src, crf_wp, pbuf);

  // ---- CRF p for self-loop-only edge rows ----
  chunk_fold_kernel<<<CFB, 256, 0, stream>>>(edge_type + (size_t)N * 64, t_e1l,
                                             e1_b, WcT, pcv, pbuf + 2 * (size_t)N, Mhigh);

  // ---- heads ----
  gemm64_kernel<64, 3><<<dim3(NB, 2), 256, 0, stream>>>(B3, px_w1, 128, px_b1, ph, 128, N);
  head_kernel<<<(N + 7) / 8, 256, 0, stream>>>(B3, ph, rowptr, csr_eid, pbuf,
                                               crf_wu, crf_bu, px_w2, px_b2, out, N);
}

// Round 13
// 385.665 us; speedup vs baseline: 1.3356x; 1.0173x over previous
//
#include <hip/hip_runtime.h>
#include <cstddef>
#include <cstdint>

#define N_NODES 20000
#define N_EDGES 320000

typedef __attribute__((ext_vector_type(8))) short bf8_t;   // 8 x bf16 (MFMA frag)
typedef __attribute__((ext_vector_type(4))) float f4_t;    // MFMA acc / float4
typedef __attribute__((ext_vector_type(2))) float f2_t;
typedef unsigned short bfu;
typedef _Float16 half_t;
typedef __attribute__((ext_vector_type(2))) _Float16 h2_t;
typedef __attribute__((ext_vector_type(4))) _Float16 h4_t;
typedef __attribute__((ext_vector_type(8))) _Float16 h8_t;

__device__ __forceinline__ short f2bf(float f) {
  unsigned u = __float_as_uint(f);
  u += 0x7fff + ((u >> 16) & 1);   // round-to-nearest-even
  return (short)(u >> 16);
}
// |t| on packed f16 (clear sign bits)
__device__ __forceinline__ h2_t abs_h2(h2_t t) {
  unsigned u = __builtin_bit_cast(unsigned, t) & 0x7fff7fffu;
  return __builtin_bit_cast(h2_t, u);
}
__device__ __forceinline__ float dot2h(h2_t a, h2_t b, float c) {
#if __has_builtin(__builtin_amdgcn_fdot2)
  return __builtin_amdgcn_fdot2(a, b, c, false);
#else
  return c + (float)a.x * (float)b.x + (float)a.y * (float)b.y;
#endif
}

// ======================= CSR build =======================
__global__ void count_deg_kernel(const int* __restrict__ dst, int* __restrict__ deg, int e_cnt) {
  int e = blockIdx.x * blockDim.x + threadIdx.x;
  if (e < e_cnt) atomicAdd(&deg[dst[e]], 1);
}

__global__ __launch_bounds__(1024) void scan_kernel(
    const int* __restrict__ deg, int* __restrict__ rowptr,
    int* __restrict__ cursor, int n) {
  __shared__ int sdata[1024];
  constexpr int CH = (N_NODES + 1023) / 1024;   // compile-time -> loc[] stays in regs
  int tid = threadIdx.x;
  int base = tid * CH;
  int loc[CH];
  int s = 0;
  #pragma unroll
  for (int j = 0; j < CH; ++j) {
    int idx = base + j;
    int v = (idx < n) ? deg[idx] : 0;
    loc[j] = s;
    s += v;
  }
  sdata[tid] = s;
  __syncthreads();
  for (int off = 1; off < 1024; off <<= 1) {
    int t = (tid >= off) ? sdata[tid - off] : 0;
    __syncthreads();
    sdata[tid] += t;
    __syncthreads();
  }
  int excl = sdata[tid] - s;
  #pragma unroll
  for (int j = 0; j < CH; ++j) {
    int idx = base + j;
    if (idx < n) { int val = excl + loc[j]; rowptr[idx] = val; cursor[idx] = val; }
  }
  if (tid == 0) rowptr[n] = sdata[1023];
}

__global__ void fill_csr_kernel(const int* __restrict__ src, const int* __restrict__ dst,
                                int* __restrict__ cursor, int* __restrict__ csr_src,
                                int* __restrict__ csr_eid, int e_cnt) {
  int e = blockIdx.x * blockDim.x + threadIdx.x;
  if (e < e_cnt) {
    int pos = atomicAdd(&cursor[dst[e]], 1);
    csr_src[pos] = src[e];
    csr_eid[pos] = e;
  }
}

// ======================= weight prep =======================
__global__ void prep_all_kernel(
    const float* __restrict__ n1l, const float* __restrict__ n1r,
    const float* __restrict__ e1l, const float* __restrict__ e1r,
    const float* __restrict__ n2l, const float* __restrict__ n2r,
    const float* __restrict__ e2l, const float* __restrict__ e2r,
    const float* __restrict__ b2, const float* __restrict__ wp,
    short* __restrict__ t_n1l, short* __restrict__ t_n1r,
    short* __restrict__ t_e1l, short* __restrict__ t_e1r,
    short* __restrict__ t_n2l, short* __restrict__ t_n2r,
    short* __restrict__ t_e2l, short* __restrict__ t_e2r,
    float* __restrict__ wct, float* __restrict__ pc)
{
  int i = blockIdx.x * blockDim.x + threadIdx.x;
  int seg = i >> 14;
  int j = i & 16383;
  if (seg < 4) {
    const float* srcs[4] = {n1l, n1r, e1l, e1r};
    short* dsts[4] = {t_n1l, t_n1r, t_e1l, t_e1r};
    int n = j >> 6, k = j & 63;
    dsts[seg][n * 64 + k] = f2bf(srcs[seg][k * 256 + n]);
  } else if (seg < 8) {
    const float* srcs[4] = {n2l, n2r, e2l, e2r};
    short* dsts[4] = {t_n2l, t_n2r, t_e2l, t_e2r};
    int n = j >> 8, k = j & 255;
    dsts[seg - 4][n * 256 + k] = f2bf(srcs[seg - 4][k * 64 + n]);
  } else if (seg == 8) {
    if (j < 512) {
      int jj = j & 1;
      int k  = j >> 1;
      float s = 0.f;
      for (int c = 0; c < 64; ++c) s = fmaf(e2l[k * 64 + c], wp[c * 2 + jj], s);
      wct[jj * 256 + k] = s;
    } else if (j < 514) {
      int jj = j - 512;
      float s = 0.f;
      for (int c = 0; c < 64; ++c) s = fmaf(b2[c], wp[c * 2 + jj], s);
      pc[jj] = s;
    }
  }
}

// ======================= MFMA projection kernel (dual-chain, fp16 outputs) ==========
// YM = y-slices merged per block: the A-tile fragments are loaded ONCE and reused
// across YM heads (proj1's old grid re-read the same A-tile 8x -> ~82 MB redundant
// fetch). YM=2 keeps 2504 blocks (≈5 waves/SIMD, no latency cliff). Requires YM to
// divide nslices so a block never mixes l/r sides.
template<int K, int YM, typename SrcT>
__global__ __launch_bounds__(128) void mfma_proj2_kernel(
    const SrcT* __restrict__ A0,
    const short* __restrict__ Wtl0, const short* __restrict__ Wtr0,
    half_t* __restrict__ xl0, half_t* __restrict__ xr0,
    const SrcT* __restrict__ A1,
    const short* __restrict__ Wtl1, const short* __restrict__ Wtr1,
    half_t* __restrict__ xl1, half_t* __restrict__ xr1,
    const float* __restrict__ att0, const float* __restrict__ att1,
    float* __restrict__ ll0, float* __restrict__ lr0,
    float* __restrict__ ll1, float* __restrict__ lr1,
    int M, int nslices)
{
  constexpr int KC = K / 32;
  int tid = threadIdx.x;
  int w = tid >> 6, lane = tid & 63, quad = lane >> 4, l15 = lane & 15;
  int row_base = (int)blockIdx.x * 64 + w * 32;
  int by = (int)blockIdx.y;
  int z = (int)blockIdx.z;
  const SrcT* A = z ? A1 : A0;
  const float* att = z ? att1 : att0;
  int STR = nslices * 64;

  // ---- A fragments: loaded once, reused for all YM heads ----
  bf8_t a[2][KC];
  #pragma unroll
  for (int rt = 0; rt < 2; ++rt) {
    int r = row_base + rt * 16 + l15;
    int rc = r < M ? r : M - 1;
    const SrcT* ap = A + (size_t)rc * K + quad * 8;
    #pragma unroll
    for (int kc = 0; kc < KC; ++kc) {
      bf8_t f;
      if constexpr (sizeof(SrcT) == 4) {
        float4 v0 = *(const float4*)(ap + kc * 32);
        float4 v1 = *(const float4*)(ap + kc * 32 + 4);
        f[0] = f2bf(v0.x); f[1] = f2bf(v0.y); f[2] = f2bf(v0.z); f[3] = f2bf(v0.w);
        f[4] = f2bf(v1.x); f[5] = f2bf(v1.y); f[6] = f2bf(v1.z); f[7] = f2bf(v1.w);
      } else {
        h8_t hv = *(const h8_t*)(ap + kc * 32);
        #pragma unroll
        for (int q = 0; q < 8; ++q) f[q] = f2bf((float)hv[q]);
      }
      a[rt][kc] = f;
    }
  }

  #pragma unroll
  for (int hi = 0; hi < YM; ++hi) {
    int y = by * YM + hi;
    bool is_l = y < nslices;
    const short* Wt = z ? (is_l ? Wtl1 : Wtr1) : (is_l ? Wtl0 : Wtr0);
    half_t* dst = z ? (is_l ? xl1 : xr1) : (is_l ? xl0 : xr0);
    float* lin = z ? (is_l ? ll1 : lr1) : (is_l ? ll0 : lr0);
    int head = is_l ? y : y - nslices;
    int cb = head * 64;
    const float* atp = att + head * 64;

    float lacc0 = 0.f, lacc1 = 0.f;
    #pragma unroll
    for (int nt = 0; nt < 4; ++nt) {
      f4_t acc0 = {0.f, 0.f, 0.f, 0.f};
      f4_t acc1 = {0.f, 0.f, 0.f, 0.f};
      const short* wb = Wt + (size_t)(cb + nt * 16 + l15) * K + quad * 8;
      #pragma unroll
      for (int kc = 0; kc < KC; ++kc) {
        bf8_t wf = *(const bf8_t*)(wb + kc * 32);
        acc0 = __builtin_amdgcn_mfma_f32_16x16x32_bf16(wf, a[0][kc], acc0, 0, 0, 0);
        acc1 = __builtin_amdgcn_mfma_f32_16x16x32_bf16(wf, a[1][kc], acc1, 0, 0, 0);
      }
      // att-dot for the linear logit part (cols nt*16 + quad*4 + j of this head)
      f4_t av = *(const f4_t*)(atp + nt * 16 + quad * 4);
      lacc0 += acc0[0] * av[0] + acc0[1] * av[1] + acc0[2] * av[2] + acc0[3] * av[3];
      lacc1 += acc1[0] * av[0] + acc1[1] * av[1] + acc1[2] * av[2] + acc1[3] * av[3];
      #pragma unroll
      for (int rt = 0; rt < 2; ++rt) {
        f4_t acc = rt == 0 ? acc0 : acc1;
        int row = row_base + rt * 16 + l15;
        if (row >= M) continue;
        int col = cb + nt * 16 + quad * 4;
        h4_t pk;
        pk[0] = (_Float16)acc[0]; pk[1] = (_Float16)acc[1];
        pk[2] = (_Float16)acc[2]; pk[3] = (_Float16)acc[3];
        *(h4_t*)&dst[(size_t)row * STR + col] = pk;
      }
    }
    // reduce lacc across the 4 quads (each quad covered a disjoint col subset)
    lacc0 += __shfl_xor(lacc0, 16, 64); lacc0 += __shfl_xor(lacc0, 32, 64);
    lacc1 += __shfl_xor(lacc1, 16, 64); lacc1 += __shfl_xor(lacc1, 32, 64);
    if (quad == 0) {
      int r0 = row_base + l15;
      int r1 = row_base + 16 + l15;
      if (r0 < M) lin[(size_t)r0 * nslices + head] = 0.6f * lacc0;
      if (r1 < M) lin[(size_t)r1 * nslices + head] = 0.6f * lacc1;
    }
  }
}

// ======================= fp32 GEMM (proxy head only) =======================
template<int KIN>
__device__ __forceinline__ void gemm_body(
    const float* __restrict__ A, const float* __restrict__ W, int wld, int cb,
    int block_m, int M, float (&acc)[8][4],
    float (*As)[128 + 4], float (*Ws)[64 + 4])
{
  int tid = threadIdx.x;
  int tx = tid & 15;
  int ty = tid >> 4;
  #pragma unroll
  for (int i = 0; i < 8; ++i)
    #pragma unroll
    for (int j = 0; j < 4; ++j) acc[i][j] = 0.f;

  for (int k0 = 0; k0 < KIN; k0 += 16) {
    #pragma unroll
    for (int rep = 0; rep < 2; ++rep) {
      int ar = (tid >> 2) + rep * 64;
      int ak = (tid & 3) * 4;
      int gr = block_m + ar;
      float4 v = make_float4(0.f, 0.f, 0.f, 0.f);
      if (gr < M) v = *(const float4*)&A[(size_t)gr * KIN + k0 + ak];
      As[ak + 0][ar] = v.x; As[ak + 1][ar] = v.y;
      As[ak + 2][ar] = v.z; As[ak + 3][ar] = v.w;
    }
    {
      int wr = tid >> 4;
      int wc = (tid & 15) * 4;
      float4 v = *(const float4*)&W[(size_t)(k0 + wr) * wld + cb + wc];
      Ws[wr][wc + 0] = v.x; Ws[wr][wc + 1] = v.y;
      Ws[wr][wc + 2] = v.z; Ws[wr][wc + 3] = v.w;
    }
    __syncthreads();
    #pragma unroll
    for (int k = 0; k < 16; ++k) {
      float a[8], w[4];
      #pragma unroll
      for (int i = 0; i < 8; ++i) a[i] = As[k][ty * 8 + i];
      #pragma unroll
      for (int j = 0; j < 4; ++j) w[j] = Ws[k][tx * 4 + j];
      #pragma unroll
      for (int i = 0; i < 8; ++i)
        #pragma unroll
        for (int j = 0; j < 4; ++j) acc[i][j] = fmaf(a[i], w[j], acc[i][j]);
    }
    __syncthreads();
  }
}

template<int KIN, int MODE>
__global__ __launch_bounds__(256) void gemm64_kernel(
    const float* __restrict__ A, const float* __restrict__ W, int wld,
    const float* __restrict__ bias, float* __restrict__ out, int old, int M)
{
  __shared__ float As[16][128 + 4];
  __shared__ float Ws[16][64 + 4];
  float acc[8][4];
  int block_m = (int)blockIdx.x * 128;
  int cb = (int)blockIdx.y * 64;
  gemm_body<KIN>(A, W, wld, cb, block_m, M, acc, As, Ws);

  int tid = threadIdx.x;
  int tx = tid & 15, ty = tid >> 4;
  int gc = cb + tx * 4;
  #pragma unroll
  for (int i = 0; i < 8; ++i) {
    int gr = block_m + ty * 8 + i;
    if (gr >= M) continue;
    size_t idx = (size_t)gr * old + gc;
    float t0 = acc[i][0], t1 = acc[i][1], t2 = acc[i][2], t3 = acc[i][3];
    if (MODE == 3) {
      t0 = fmaxf(t0 + bias[gc + 0], 0.f);
      t1 = fmaxf(t1 + bias[gc + 1], 0.f);
      t2 = fmaxf(t2 + bias[gc + 2], 0.f);
      t3 = fmaxf(t3 + bias[gc + 3], 0.f);
    }
    *(float4*)&out[idx] = make_float4(t0, t1, t2, t3);
  }
}

// ======================= GATv2 aggregation, layer 1 (4 heads fused per wave) ==========
// Lane layout: egrp = lane>>5 (2 edge slots), head = (lane>>3)&3, cch = lane&7.
// Column offset = (lane&31)*8 covers all 256 channels per half-wave (coalesced 512B).
// Logit uses leaky decomposition: logit = linL[s,h] + linR[d,h] + dot(|xl+xr|, 0.4*att).
// Output h (post-ELU) stored as fp16.
__global__ __launch_bounds__(256) void gat_agg_l1(
    const half_t* __restrict__ xl0, const half_t* __restrict__ xr0,
    const float* __restrict__ att0, const float* __restrict__ bias0,
    half_t* __restrict__ out0,
    const half_t* __restrict__ xl1, const half_t* __restrict__ xr1,
    const float* __restrict__ att1, const float* __restrict__ bias1,
    half_t* __restrict__ out1,
    const float* __restrict__ ll0, const float* __restrict__ lr0,
    const float* __restrict__ ll1, const float* __restrict__ lr1,
    const int* __restrict__ rowptr, const int* __restrict__ csr_src)
{
  constexpr int GRP = N_NODES / 4;
  int tid = threadIdx.x;
  int w = tid >> 6, lane = tid & 63;
  int egrp = lane >> 5;
  int head = (lane >> 3) & 3;
  int coff = (lane & 31) * 8;
  int bid = (int)blockIdx.x;
  int chain = bid >= GRP ? 1 : 0;
  int d = (bid - chain * GRP) * 4 + w;

  const half_t* xl = chain ? xl1 : xl0;
  const half_t* xr = chain ? xr1 : xr0;
  const float* att = chain ? att1 : att0;
  const float* bias = chain ? bias1 : bias0;
  const float* linl = chain ? ll1 : ll0;
  const float* linr = chain ? lr1 : lr0;
  half_t* out = chain ? out1 : out0;

  int row0 = rowptr[d];
  int deg = rowptr[d + 1] - row0;

  h2_t xr2[4], attA[4];
  {
    h8_t xv = *(const h8_t*)&xr[(unsigned)(d * 256 + coff)];
    xr2[0] = h2_t{xv[0], xv[1]}; xr2[1] = h2_t{xv[2], xv[3]};
    xr2[2] = h2_t{xv[4], xv[5]}; xr2[3] = h2_t{xv[6], xv[7]};
    const float* atp = att + coff;
    float4 b0 = *(const float4*)(atp);
    float4 b1 = *(const float4*)(atp + 4);
    attA[0] = h2_t{(_Float16)(0.4f * b0.x), (_Float16)(0.4f * b0.y)};
    attA[1] = h2_t{(_Float16)(0.4f * b0.z), (_Float16)(0.4f * b0.w)};
    attA[2] = h2_t{(_Float16)(0.4f * b1.x), (_Float16)(0.4f * b1.y)};
    attA[3] = h2_t{(_Float16)(0.4f * b1.z), (_Float16)(0.4f * b1.w)};
  }
  float linr_d = linr[(unsigned)(d * 4 + head)];

  auto ld_idx = [&](int k) -> int {
    int idx = k * 2 + egrp;
    int cl = idx < deg ? idx : (deg > 0 ? deg - 1 : 0);
    int pos = deg > 0 ? row0 + cl : 0;
    int sv = csr_src[pos];
    return idx < deg ? sv : d;
  };

  float zloc, a8[8];
  {
    // self loop (counted once via egrp==0 mask)
    h8_t xu = *(const h8_t*)&xl[(unsigned)(d * 256 + coff)];
    float part = 0.f;
    #pragma unroll
    for (int j = 0; j < 4; ++j) {
      h2_t t = h2_t{xu[2 * j], xu[2 * j + 1]} + xr2[j];
      part = dot2h(abs_h2(t), attA[j], part);
    }
    part += __shfl_xor(part, 1, 64);
    part += __shfl_xor(part, 2, 64);
    part += __shfl_xor(part, 4, 64);
    part += linl[(unsigned)(d * 4 + head)] + linr_d;
    float wgt = __expf(part);
    float ws = (egrp == 0) ? wgt : 0.f;
    zloc = ws;
    #pragma unroll
    for (int i = 0; i < 8; ++i) a8[i] = (float)xu[i] * ws;
  }

  int C = (deg + 1) >> 1;
  int s_cur = ld_idx(0);
  h8_t xu_cur = *(const h8_t*)&xl[(unsigned)(s_cur * 256 + coff)];
  float lin_cur = linl[(unsigned)(s_cur * 4 + head)];
  int s_nxt = ld_idx(1);
  for (int k = 0; k < C; ++k) {
    h8_t xu_nxt = *(const h8_t*)&xl[(unsigned)(s_nxt * 256 + coff)];
    float lin_nxt = linl[(unsigned)(s_nxt * 4 + head)];
    int s_n2 = ld_idx(k + 2);
    bool valid = (k * 2 + egrp) < deg;
    float part = 0.f;
    #pragma unroll
    for (int j = 0; j < 4; ++j) {
      h2_t t = h2_t{xu_cur[2 * j], xu_cur[2 * j + 1]} + xr2[j];
      part = dot2h(abs_h2(t), attA[j], part);
    }
    part += __shfl_xor(part, 1, 64);
    part += __shfl_xor(part, 2, 64);
    part += __shfl_xor(part, 4, 64);
    part += lin_cur + linr_d;
    float wgt = valid ? __expf(part) : 0.f;
    zloc += wgt;
    #pragma unroll
    for (int i = 0; i < 8; ++i) a8[i] = fmaf((float)xu_cur[i], wgt, a8[i]);
    xu_cur = xu_nxt; lin_cur = lin_nxt; s_nxt = s_n2;
  }

  // combine the two edge-slot halves
  zloc += __shfl_xor(zloc, 32, 64);
  #pragma unroll
  for (int i = 0; i < 8; ++i) a8[i] += __shfl_xor(a8[i], 32, 64);

  if (egrp == 0) {
    float invz = 1.f / zloc;
    const float* bp = bias + coff;
    float4 c0 = *(const float4*)(bp);
    float4 c1 = *(const float4*)(bp + 4);
    float o[8];
    o[0] = a8[0] * invz + c0.x; o[1] = a8[1] * invz + c0.y;
    o[2] = a8[2] * invz + c0.z; o[3] = a8[3] * invz + c0.w;
    o[4] = a8[4] * invz + c1.x; o[5] = a8[5] * invz + c1.y;
    o[6] = a8[6] * invz + c1.z; o[7] = a8[7] * invz + c1.w;
    #pragma unroll
    for (int i = 0; i < 8; ++i) o[i] = o[i] > 0.f ? o[i] : __expf(o[i]) - 1.f;  // ELU
    h8_t pk;
    #pragma unroll
    for (int i = 0; i < 8; ++i) pk[i] = (_Float16)o[i];
    *(h8_t*)&out[(size_t)d * 256 + coff] = pk;   // single 16B fp16 store
  }
}

// ======================= GATv2 aggregation, layer 2 (1 head, abs-trick, fused p) ======
__global__ __launch_bounds__(256) void gat_agg_l2(
    const half_t* __restrict__ xl0, const half_t* __restrict__ xr0,
    const float* __restrict__ att0, const float* __restrict__ bias0,
    float* __restrict__ out0,
    const half_t* __restrict__ xl1, const half_t* __restrict__ xr1,
    const float* __restrict__ att1, const float* __restrict__ bias1,
    const float* __restrict__ ll0, const float* __restrict__ lr0,
    const float* __restrict__ ll1, const float* __restrict__ lr1,
    const int* __restrict__ rowptr, const int* __restrict__ csr_src,
    const float* __restrict__ wp, float* __restrict__ pbuf)
{
  constexpr int GRP = N_NODES / 4;
  int tid = threadIdx.x;
  int w = tid >> 6;
  int lane = tid & 63;
  int egrp = lane >> 3;
  int cch  = lane & 7;
  int bid = (int)blockIdx.x;
  int chain = bid >= GRP ? 1 : 0;
  int d = (bid - chain * GRP) * 4 + w;

  const half_t* xl = chain ? xl1 : xl0;
  const half_t* xr = chain ? xr1 : xr0;
  const float* att = chain ? att1 : att0;
  const float* bias = chain ? bias1 : bias0;
  const float* linl = chain ? ll1 : ll0;
  const float* linr = chain ? lr1 : lr0;

  int row0 = rowptr[d];
  int deg = rowptr[d + 1] - row0;
  int cbase = cch * 8;

  h2_t xr2[4], attA[4];
  {
    h8_t xv = *(const h8_t*)&xr[(unsigned)(d * 64 + cbase)];
    xr2[0] = h2_t{xv[0], xv[1]}; xr2[1] = h2_t{xv[2], xv[3]};
    xr2[2] = h2_t{xv[4], xv[5]}; xr2[3] = h2_t{xv[6], xv[7]};
    const float* atp = att + cbase;
    float4 b0 = *(const float4*)(atp);
    float4 b1 = *(const float4*)(atp + 4);
    attA[0] = h2_t{(_Float16)(0.4f * b0.x), (_Float16)(0.4f * b0.y)};
    attA[1] = h2_t{(_Float16)(0.4f * b0.z), (_Float16)(0.4f * b0.w)};
    attA[2] = h2_t{(_Float16)(0.4f * b1.x), (_Float16)(0.4f * b1.y)};
    attA[3] = h2_t{(_Float16)(0.4f * b1.z), (_Float16)(0.4f * b1.w)};
  }
  float linr_d = linr[d];

  auto ld_idx = [&](int k) -> int {
    int idx = k * 8 + egrp;
    int cl = idx < deg ? idx : (deg > 0 ? deg - 1 : 0);
    int pos = deg > 0 ? row0 + cl : 0;
    int sv = csr_src[pos];
    return idx < deg ? sv : d;
  };

  float zloc, a8[8];
  {
    h8_t xu = *(const h8_t*)&xl[(unsigned)(d * 64 + cbase)];
    float part = 0.f;
    #pragma unroll
    for (int j = 0; j < 4; ++j) {
      h2_t t = h2_t{xu[2 * j], xu[2 * j + 1]} + xr2[j];
      part = dot2h(abs_h2(t), attA[j], part);
    }
    part += __shfl_xor(part, 1, 64);
    part += __shfl_xor(part, 2, 64);
    part += __shfl_xor(part, 4, 64);
    part += linl[d] + linr_d;
    float wgt = __expf(part);
    float ws = (egrp == 0) ? wgt : 0.f;
    zloc = ws;
    #pragma unroll
    for (int i = 0; i < 8; ++i) a8[i] = (float)xu[i] * ws;
  }

  int C = (deg + 7) >> 3;
  int s_cur = ld_idx(0);
  h8_t xu_cur = *(const h8_t*)&xl[(unsigned)(s_cur * 64 + cbase)];
  float lin_cur = linl[s_cur];
  int s_nxt = ld_idx(1);
  for (int k = 0; k < C; ++k) {
    h8_t xu_nxt = *(const h8_t*)&xl[(unsigned)(s_nxt * 64 + cbase)];
    float lin_nxt = linl[s_nxt];
    int s_n2 = ld_idx(k + 2);
    bool valid = (k * 8 + egrp) < deg;
    float part = 0.f;
    #pragma unroll
    for (int j = 0; j < 4; ++j) {
      h2_t t = h2_t{xu_cur[2 * j], xu_cur[2 * j + 1]} + xr2[j];
      part = dot2h(abs_h2(t), attA[j], part);
    }
    part += __shfl_xor(part, 1, 64);
    part += __shfl_xor(part, 2, 64);
    part += __shfl_xor(part, 4, 64);
    part += lin_cur + linr_d;
    float wgt = valid ? __expf(part) : 0.f;
    zloc += wgt;
    #pragma unroll
    for (int i = 0; i < 8; ++i) a8[i] = fmaf((float)xu_cur[i], wgt, a8[i]);
    xu_cur = xu_nxt; lin_cur = lin_nxt; s_nxt = s_n2;
  }

  #pragma unroll
  for (int off = 8; off < 64; off <<= 1) {
    zloc += __shfl_xor(zloc, off, 64);
    #pragma unroll
    for (int i = 0; i < 8; ++i) a8[i] += __shfl_xor(a8[i], off, 64);
  }

  float invz = 1.f / zloc;
  float o[8];
  #pragma unroll
  for (int i = 0; i < 8; ++i) o[i] = a8[i] * invz + bias[cbase + i];

  if (chain) {
    // fold directly into CRF pairwise message p = (out) @ wp
    float p0 = 0.f, p1 = 0.f;
    #pragma unroll
    for (int i = 0; i < 8; ++i) {
      float2 wv = *(const float2*)&wp[(cbase + i) * 2];
      p0 = fmaf(o[i], wv.x, p0);
      p1 = fmaf(o[i], wv.y, p1);
    }
    p0 += __shfl_xor(p0, 1, 64); p1 += __shfl_xor(p1, 1, 64);
    p0 += __shfl_xor(p0, 2, 64); p1 += __shfl_xor(p1, 2, 64);
    p0 += __shfl_xor(p0, 4, 64); p1 += __shfl_xor(p1, 4, 64);
    if (lane == 0) *(float2*)&pbuf[2 * d] = make_float2(p0, p1);
  } else if (egrp == 0) {
    float* op = out0 + (size_t)d * 64 + cbase;
    *(float4*)(op)     = make_float4(o[0], o[1], o[2], o[3]);
    *(float4*)(op + 4) = make_float4(o[4], o[5], o[6], o[7]);
  }
}

// ======================= folded chunk kernel v8 (W in LDS, spill-free) ===============
__global__ __launch_bounds__(256) void chunk_fold_kernel(
    const float* __restrict__ A,
    const short* __restrict__ W1t,
    const float* __restrict__ b1,
    const float* __restrict__ WcT,
    const float* __restrict__ pc,
    float* __restrict__ pbufN,
    int Mtot)
{
  __shared__ short Ws[256 * 72];   // 36864 B, stride 72 shorts = bank-balanced for b128
  __shared__ float b1s[256];
  __shared__ float wcs[512];

  int tid = threadIdx.x;
  int w = tid >> 6;
  int lane = tid & 63;
  int quad = lane >> 4;
  int l15 = lane & 15;
  int row_base = (int)blockIdx.x * 256 + w * 64;

  // Phase 1: cooperative staging of W (32 KB) + tables into LDS.
  #pragma unroll
  for (int j = 0; j < 8; ++j) {
    int g = j * 256 + tid;
    int row = g >> 3, c = g & 7;
    *(int4*)&Ws[row * 72 + c * 8] = *(const int4*)&W1t[(size_t)g * 8];
  }
  b1s[tid] = b1[tid];
  wcs[tid] = WcT[tid];
  wcs[256 + tid] = WcT[256 + tid];
  __syncthreads();

  // Phase 2: A load + convert (no liveness across the barrier)
  bf8_t a1[4][2];
  #pragma unroll
  for (int rt = 0; rt < 4; ++rt) {
    int r = row_base + rt * 16 + l15;
    int rc = r < Mtot ? r : Mtot - 1;
    const float* ap = A + (size_t)rc * 64 + quad * 8;
    #pragma unroll
    for (int ks = 0; ks < 2; ++ks) {
      float4 v0 = *(const float4*)(ap + ks * 32);
      float4 v1 = *(const float4*)(ap + ks * 32 + 4);
      bf8_t f;
      f[0] = f2bf(v0.x); f[1] = f2bf(v0.y); f[2] = f2bf(v0.z); f[3] = f2bf(v0.w);
      f[4] = f2bf(v1.x); f[5] = f2bf(v1.y); f[6] = f2bf(v1.z); f[7] = f2bf(v1.w);
      a1[rt][ks] = f;
    }
  }

  float p0[4] = {0.f, 0.f, 0.f, 0.f};
  float p1[4] = {0.f, 0.f, 0.f, 0.f};

  // Phase 3: 16-iteration loop, LDS + registers only.
  #pragma unroll
  for (int i = 0; i < 16; ++i) {
    const short* wl = &Ws[(i * 16 + l15) * 72 + quad * 8];
    bf8_t w0 = *(const bf8_t*)(wl);
    bf8_t w1 = *(const bf8_t*)(wl + 32);

    f4_t g[4];
    #pragma unroll
    for (int rt = 0; rt < 4; ++rt) {
      f4_t z = {0.f, 0.f, 0.f, 0.f};
      z = __builtin_amdgcn_mfma_f32_16x16x32_bf16(w0, a1[rt][0], z, 0, 0, 0);
      z = __builtin_amdgcn_mfma_f32_16x16x32_bf16(w1, a1[rt][1], z, 0, 0, 0);
      g[rt] = z;
    }
    int cbase = i * 16 + quad * 4;
    f4_t b4  = *(const f4_t*)&b1s[cbase];
    f4_t wc0 = *(const f4_t*)&wcs[cbase];
    f4_t wc1 = *(const f4_t*)&wcs[256 + cbase];
    #pragma unroll
    for (int rt = 0; rt < 4; ++rt) {
      #pragma unroll
      for (int r = 0; r < 4; ++r) {
        float v = g[rt][r] + b4[r];
        v = v > 0.f ? v : __expf(v) - 1.f;
        p0[rt] = fmaf(v, wc0[r], p0[rt]);
        p1[rt] = fmaf(v, wc1[r], p1[rt]);
      }
    }
  }

  #pragma unroll
  for (int off = 16; off < 64; off <<= 1) {
    #pragma unroll
    for (int rt = 0; rt < 4; ++rt) {
      p0[rt] += __shfl_xor(p0[rt], off, 64);
      p1[rt] += __shfl_xor(p1[rt], off, 64);
    }
  }
  if (quad == 0) {
    float c0 = pc[0], c1 = pc[1];
    #pragma unroll
    for (int rt = 0; rt < 4; ++rt) {
      int row = row_base + rt * 16 + l15;
      if (row < Mtot)
        *(float2*)&pbufN[2 * row] = make_float2(p0[rt] + c0, p1[rt] + c1);
    }
  }
}

// ======================= Heads (half-wave per node) =======================
__global__ __launch_bounds__(256) void head_kernel(
    const float* __restrict__ node_repr, const float* __restrict__ ph,
    const int* __restrict__ rowptr, const int* __restrict__ csr_eid,
    const float* __restrict__ pbuf, const float* __restrict__ wu,
    const float* __restrict__ bu, const float* __restrict__ w2,
    const float* __restrict__ b2, float* __restrict__ out, int n) {
  int tid = threadIdx.x;
  int half = tid >> 5;          // 8 half-waves per block
  int lane32 = tid & 31;
  int i = blockIdx.x * 8 + half;
  if (i >= n) return;

  // pairwise message sum over this node's incoming edges (lanes stride the list)
  float m0 = 0.f, m1 = 0.f;
  int r0 = rowptr[i], r1 = rowptr[i + 1];
  for (int jj = r0 + lane32; jj < r1; jj += 32) {
    int e = csr_eid[jj];
    float2 q = *(const float2*)&pbuf[2 * e];
    m0 += q.x; m1 += q.y;
  }
  // unary: channels 2*lane32, 2*lane32+1 (wu is [64][2] row-major)
  {
    float2 nv = *(const float2*)&node_repr[(size_t)i * 64 + 2 * lane32];
    float4 wv = *(const float4*)&wu[4 * lane32];
    m0 = fmaf(nv.x, wv.x, fmaf(nv.y, wv.z, m0));
    m1 = fmaf(nv.x, wv.y, fmaf(nv.y, wv.w, m1));
  }
  // proxy: channels 4*lane32 .. +3 (w2 is [128][2] row-major)
  float p0, p1;
  {
    float4 pv  = *(const float4*)&ph[(size_t)i * 128 + 4 * lane32];
    float4 w20 = *(const float4*)&w2[8 * lane32];
    float4 w21 = *(const float4*)&w2[8 * lane32 + 4];
    p0 = pv.x * w20.x + pv.y * w20.z + pv.z * w21.x + pv.w * w21.z;
    p1 = pv.x * w20.y + pv.y * w20.w + pv.z * w21.y + pv.w * w21.w;
  }
  // width-32 reduce (xor offsets < 32 stay within the half-wave)
  #pragma unroll
  for (int off = 1; off < 32; off <<= 1) {
    m0 += __shfl_xor(m0, off, 64);
    m1 += __shfl_xor(m1, off, 64);
    p0 += __shfl_xor(p0, off, 64);
    p1 += __shfl_xor(p1, off, 64);
  }
  if (lane32 == 0) {
    float v0 = m0 + bu[0], v1 = m1 + bu[1];
    float mx = fmaxf(v0, v1);
    float lse = mx + logf(__expf(v0 - mx) + __expf(v1 - mx));
    out[2 * i + 0] = v0 - lse;
    out[2 * i + 1] = v1 - lse;
    out[2 * n + 2 * i + 0] = p0 + b2[0];
    out[2 * n + 2 * i + 1] = p1 + b2[1];
  }
}

// ======================= launch =======================
extern "C" void kernel_launch(void* const* d_in, const int* in_sizes, int n_in,
                              void* d_out, int out_size, void* d_ws, size_t ws_size,
                              hipStream_t stream) {
  const int N = N_NODES, E = N_EDGES;
  const float* x         = (const float*)d_in[0];
  const float* edge_type = (const float*)d_in[1];
  const int*   ei        = (const int*)d_in[2];
  const float* n1_wl  = (const float*)d_in[3];
  const float* n1_wr  = (const float*)d_in[4];
  const float* n1_att = (const float*)d_in[5];
  const float* n1_b   = (const float*)d_in[6];
  const float* n2_wl  = (const float*)d_in[7];
  const float* n2_wr  = (const float*)d_in[8];
  const float* n2_att = (const float*)d_in[9];
  const float* n2_b   = (const float*)d_in[10];
  const float* e1_wl  = (const float*)d_in[11];
  const float* e1_wr  = (const float*)d_in[12];
  const float* e1_att = (const float*)d_in[13];
  const float* e1_b   = (const float*)d_in[14];
  const float* e2_wl  = (const float*)d_in[15];
  const float* e2_wr  = (const float*)d_in[16];
  const float* e2_att = (const float*)d_in[17];
  const float* e2_b   = (const float*)d_in[18];
  const float* crf_wu = (const float*)d_in[19];
  const float* crf_bu = (const float*)d_in[20];
  const float* crf_wp = (const float*)d_in[21];
  const float* px_w1  = (const float*)d_in[22];
  const float* px_b1  = (const float*)d_in[23];
  const float* px_w2  = (const float*)d_in[24];
  const float* px_b2  = (const float*)d_in[25];
  float* out = (float*)d_out;
  const int* src = ei;
  const int* dst = ei + E;
  (void)in_sizes; (void)n_in; (void)out_size; (void)ws_size;

  // ---- workspace layout (byte-identical footprint to the verified 452 µs kernel) ----
  char* ws = (char*)d_ws;
  size_t off = 0;
  auto alloc = [&](size_t bytes) -> void* {
    void* p = ws + off;
    off += (bytes + 255) & ~(size_t)255;
    return p;
  };
  half_t* xl_n  = (half_t*)alloc((size_t)N * 256 * 2);
  half_t* xr_n  = (half_t*)alloc((size_t)N * 256 * 2);
  half_t* xl_e  = (half_t*)alloc((size_t)N * 256 * 2);
  half_t* xr_e  = (half_t*)alloc((size_t)N * 256 * 2);
  // h_n / g_e stored as fp16 (allocations keep fp32 sizes -> layout unchanged)
  half_t* h_n  = (half_t*)alloc((size_t)N * 256 * 4);
  half_t* g_e  = (half_t*)alloc((size_t)N * 256 * 4);
  half_t* xl2_n = (half_t*)alloc((size_t)N * 64 * 2);
  half_t* xr2_n = (half_t*)alloc((size_t)N * 64 * 2);
  half_t* xl2_e = (half_t*)alloc((size_t)N * 64 * 2);
  half_t* xr2_e = (half_t*)alloc((size_t)N * 64 * 2);
  float* B3    = (float*)alloc((size_t)N * 64 * 4);
  float* pbuf  = (float*)alloc((size_t)E * 2 * 4);
  float* ph    = (float*)(void*)xl_n;   // reuse 10.24 MB
  int* deg     = (int*)alloc((size_t)N * 4);
  int* rowptr  = (int*)alloc((size_t)(N + 1) * 4);
  int* cursor  = (int*)alloc((size_t)N * 4);
  int* csr_src = (int*)alloc((size_t)E * 4);
  int* csr_eid = (int*)alloc((size_t)E * 4);
  short* t_n1l = (short*)alloc((size_t)16384 * 2);
  short* t_n1r = (short*)alloc((size_t)16384 * 2);
  short* t_e1l = (short*)alloc((size_t)16384 * 2);
  short* t_e1r = (short*)alloc((size_t)16384 * 2);
  short* t_n2l = (short*)alloc((size_t)16384 * 2);
  short* t_n2r = (short*)alloc((size_t)16384 * 2);
  short* t_e2l = (short*)alloc((size_t)16384 * 2);
  short* t_e2r = (short*)alloc((size_t)16384 * 2);
  float* WcT   = (float*)alloc((size_t)2 * 256 * 4);
  float* pcv   = (float*)alloc((size_t)2 * 4);
  // layer-1 linear-logit buffers aliased into pbuf (lifetime-disjoint, see r2 notes)
  float* l1ln = pbuf;
  float* l1rn = pbuf + 80000;
  float* l1le = pbuf + 160000;
  float* l1re = pbuf + 240000;
  // layer-2 linear-logit buffers aliased into xr_n (dead after gat_agg_l1)
  float* l2base = (float*)(void*)xr_n;
  float* l2ln = l2base;
  float* l2rn = l2base + 20000;
  float* l2le = l2base + 40000;
  float* l2re = l2base + 60000;

  const int EB = (E + 255) / 256;
  const int NB = (N + 127) / 128;
  const int PB = (N + 63) / 64;
  const int Mhigh = E - N;
  const int CFB = (Mhigh + 255) / 256;   // 256-row 4-wave blocks
  const int GRP = N / 4;

  hipMemsetAsync(deg, 0, (size_t)N * 4, stream);
  count_deg_kernel<<<EB, 256, 0, stream>>>(dst, deg, E);
  scan_kernel<<<1, 1024, 0, stream>>>(deg, rowptr, cursor, N);
  fill_csr_kernel<<<EB, 256, 0, stream>>>(src, dst, cursor, csr_src, csr_eid, E);
  prep_all_kernel<<<515, 256, 0, stream>>>(n1_wl, n1_wr, e1_wl, e1_wr,
                                           n2_wl, n2_wr, e2_wl, e2_wr,
                                           e2_b, crf_wp,
                                           t_n1l, t_n1r, t_e1l, t_e1r,
                                           t_n2l, t_n2r, t_e2l, t_e2r, WcT, pcv);

  // ---- layer 1 (YM=2: A-tile loaded once per 2 heads -> A-fetch halved) ----
  mfma_proj2_kernel<64, 2, float><<<dim3(PB, 4, 2), 128, 0, stream>>>(
      x, t_n1l, t_n1r, xl_n, xr_n,
      edge_type, t_e1l, t_e1r, xl_e, xr_e,
      n1_att, e1_att, l1ln, l1rn, l1le, l1re, N, 4);
  gat_agg_l1<<<2 * GRP, 256, 0, stream>>>(
      xl_n, xr_n, n1_att, n1_b, h_n,
      xl_e, xr_e, e1_att, e1_b, g_e,
      l1ln, l1rn, l1le, l1re, rowptr, csr_src);

  // ---- layer 2 (YM=1: y=0/1 are different l/r matrices) ----
  mfma_proj2_kernel<256, 1, half_t><<<dim3(PB, 2, 2), 128, 0, stream>>>(
      h_n, t_n2l, t_n2r, xl2_n, xr2_n,
      g_e, t_e2l, t_e2r, xl2_e, xr2_e,
      n2_att, e2_att, l2ln, l2rn, l2le, l2re, N, 1);
  gat_agg_l2<<<2 * GRP, 256, 0, stream>>>(
      xl2_n, xr2_n, n2_att, n2_b, B3,
      xl2_e, xr2_e, e2_att, e2_b,
      l2ln, l2rn, l2le, l2re, rowptr, csr_src, crf_wp, pbuf);

  // ---- CRF p for self-loop-only edge rows ----
  chunk_fold_kernel<<<CFB, 256, 0, stream>>>(edge_type + (size_t)N * 64, t_e1l,
                                             e1_b, WcT, pcv, pbuf + 2 * (size_t)N, Mhigh);

  // ---- heads ----
  gemm64_kernel<64, 3><<<dim3(NB, 2), 256, 0, stream>>>(B3, px_w1, 128, px_b1, ph, 128, N);
  head_kernel<<<(N + 7) / 8, 256, 0, stream>>>(B3, ph, rowptr, csr_eid, pbuf,
                                               crf_wu, crf_bu, px_w2, px_b2, out, N);
}